// Round 14
// baseline (239.614 us; speedup 1.0000x reference)
//
#include <hip/hip_runtime.h>

// GuidedAttention on MI355X, round 14: resubmission of round 13 (infra failure
// on dead container — never ran).
// Changes vs round-12 (215us): (1) k_qkv emits V as fp8 TRANSPOSED Vt8[bh][d][j]
// (replaces bf16 V; frees k_av from V staging); Q/K stores go through an LDS
// transpose -> coalesced uint4 stores (was 64 scattered u16/thread).
// (2) k_av rewritten LDS-free/barrier-free: P fragments loaded directly from
// global (row-major fp8 matches A-frag layout), V^T fragments from L2-resident
// Vt8. k_conv/k_qk/k_proj unchanged.
// ws layout (160 MB): [Q bf16 8MB | D f32 256KB overlaid after k_qk]
//                     [K bf16 8MB][Vt8 fp8 4MB (in 8MB slot)][Z bf16 8MB]
//                     [S fp8 64MB][P fp8 64MB]

#define DINL __device__ __forceinline__
typedef unsigned short u16;
typedef unsigned int u32;
typedef unsigned long long u64;
typedef short bf16x8 __attribute__((ext_vector_type(8)));
typedef float f32x4 __attribute__((ext_vector_type(4)));
typedef float f32x2 __attribute__((ext_vector_type(2)));

DINL u16 f2bf(float f) {
  u32 u = __float_as_uint(f);
  u += 0x7fffu + ((u >> 16) & 1u);
  return (u16)(u >> 16);
}
DINL float bflo(u32 u) { return __uint_as_float(u << 16); }
DINL float bfhi(u32 u) { return __uint_as_float(u & 0xffff0000u); }
DINL u32 cvtpk_bf16(float lo, float hi) {
  u32 r;
  asm("v_cvt_pk_bf16_f32 %0, %1, %2" : "=v"(r) : "v"(lo), "v"(hi));
  return r;
}
DINL u32 pk4_fp8(float a, float b, float c, float d) {
  u32 r = 0;
  r = (u32)__builtin_amdgcn_cvt_pk_fp8_f32(a, b, (int)r, false);
  r = (u32)__builtin_amdgcn_cvt_pk_fp8_f32(c, d, (int)r, true);
  return r;
}
DINL f32x2 up2_lo(u32 w) { return __builtin_amdgcn_cvt_pk_f32_fp8((int)w, false); }
DINL f32x2 up2_hi(u32 w) { return __builtin_amdgcn_cvt_pk_f32_fp8((int)w, true); }
DINL unsigned char f2fp8(float v) {
  return (unsigned char)((u32)__builtin_amdgcn_cvt_pk_fp8_f32(v, v, 0, false) & 0xffu);
}

// ---------- Kernel 1: QKV proj, bf16 MFMA. M=8192, N=1536, K=512 ----------
// which = n0>>9 is block-uniform. Q/K: LDS-transpose epilogue -> coalesced
// uint4 stores. V: fp8 transposed Vt8[bh][d][j], one u32 store per (nr,mr).
__global__ __launch_bounds__(256) void k_qkv(const float* __restrict__ x,
                                             const float* __restrict__ w,
                                             u16* __restrict__ Q,
                                             u16* __restrict__ K,
                                             unsigned char* __restrict__ Vt8) {
  __shared__ __align__(16) u16 sPool[2][128 * 64];  // A/B staging; reused as t16
  u16* sA = sPool[0];
  u16* sB = sPool[1];
  const int tid = threadIdx.x;
  const int m0 = blockIdx.x * 128, n0 = blockIdx.y * 128;
  const int lane = tid & 63, wid = tid >> 6;
  const int wr = wid >> 1, wc = wid & 1;
  const int l15 = lane & 15, l4 = lane >> 4;
  const int row = tid >> 1, half = tid & 1, xr = row & 7;
  f32x4 acc[4][4] = {};
  for (int k0 = 0; k0 < 512; k0 += 64) {
    __syncthreads();
    {
      const float* ga = &x[(size_t)(m0 + row) * 512 + k0 + half * 32];
      const float* gb = &w[(size_t)(n0 + row) * 512 + k0 + half * 32];
#pragma unroll
      for (int q = 0; q < 4; ++q) {
        int gp = (half * 4 + q) ^ xr;
        float4 a0 = *(const float4*)&ga[q * 8];
        float4 a1 = *(const float4*)&ga[q * 8 + 4];
        uint4 pa;
        pa.x = cvtpk_bf16(a0.x, a0.y); pa.y = cvtpk_bf16(a0.z, a0.w);
        pa.z = cvtpk_bf16(a1.x, a1.y); pa.w = cvtpk_bf16(a1.z, a1.w);
        *(uint4*)&sA[row * 64 + gp * 8] = pa;
        float4 b0 = *(const float4*)&gb[q * 8];
        float4 b1 = *(const float4*)&gb[q * 8 + 4];
        uint4 pb;
        pb.x = cvtpk_bf16(b0.x, b0.y); pb.y = cvtpk_bf16(b0.z, b0.w);
        pb.z = cvtpk_bf16(b1.x, b1.y); pb.w = cvtpk_bf16(b1.z, b1.w);
        *(uint4*)&sB[row * 64 + gp * 8] = pb;
      }
    }
    __syncthreads();
#pragma unroll
    for (int ks = 0; ks < 2; ++ks) {
      bf16x8 af[4], bfr[4];
#pragma unroll
      for (int mr = 0; mr < 4; ++mr) {
        int rr = wr * 64 + mr * 16 + l15;
        af[mr] = *(bf16x8*)&sA[rr * 64 + ((ks * 4 + l4) ^ (rr & 7)) * 8];
      }
#pragma unroll
      for (int nr = 0; nr < 4; ++nr) {
        int rr = wc * 64 + nr * 16 + l15;
        bfr[nr] = *(bf16x8*)&sB[rr * 64 + ((ks * 4 + l4) ^ (rr & 7)) * 8];
      }
#pragma unroll
      for (int mr = 0; mr < 4; ++mr)
#pragma unroll
        for (int nr = 0; nr < 4; ++nr)
          acc[mr][nr] = __builtin_amdgcn_mfma_f32_16x16x32_bf16(af[mr], bfr[nr],
                                                                acc[mr][nr], 0, 0, 0);
    }
  }
  const int which = n0 >> 9;  // uniform per block (128 | 512)
  if (which == 2) {
    // V: direct transposed fp8 stores (4 consecutive ii per lane -> u32).
#pragma unroll
    for (int nr = 0; nr < 4; ++nr) {
      int nn = n0 + wc * 64 + nr * 16 + l15;
      int co = nn & 511;
      int head = co >> 6, d = co & 63;
#pragma unroll
      for (int mr = 0; mr < 4; ++mr) {
        int mb = m0 + wr * 64 + mr * 16 + l4 * 4;
        int bb = mb >> 10, ii = mb & 1023;
        u32 pw = pk4_fp8(acc[mr][nr][0], acc[mr][nr][1], acc[mr][nr][2],
                         acc[mr][nr][3]);
        *(u32*)&Vt8[(((size_t)(bb * 8 + head)) << 16) + (size_t)d * 1024 + ii] = pw;
      }
    }
  } else {
    u16* dstbuf = (which == 0) ? Q : K;
    const float sc = (which == 0) ? 0.125f : 1.f;
    u16* t16 = sPool[0];  // [128][128] u16 spans both halves (32KB)
    __syncthreads();
#pragma unroll
    for (int mr = 0; mr < 4; ++mr) {
      int mloc = wr * 64 + mr * 16 + l4 * 4;
#pragma unroll
      for (int nr = 0; nr < 4; ++nr) {
        int nloc = wc * 64 + nr * 16 + l15;
#pragma unroll
        for (int r = 0; r < 4; ++r)
          t16[(mloc + r) * 128 + nloc] = f2bf(acc[mr][nr][r] * sc);
      }
    }
    __syncthreads();
    int rw = tid >> 1, c0 = (tid & 1) * 64;
    int m = m0 + rw, bb = m >> 10, ii = m & 1023;
    int head = ((n0 & 511) + c0) >> 6;
    u16* dst = dstbuf + ((((size_t)(bb * 8 + head)) << 10) + ii) * 64;
    const u16* src = &t16[rw * 128 + c0];
#pragma unroll
    for (int q = 0; q < 8; ++q)
      *(uint4*)&dst[q * 8] = *(const uint4*)&src[q * 8];
  }
}

// ---------- Kernel 2: S = Q @ K^T per (b,h), bf16 MFMA, out fp8 ----------
__global__ __launch_bounds__(256) void k_qk(const u16* __restrict__ Q,
                                            const u16* __restrict__ Kp,
                                            unsigned char* __restrict__ S8) {
  const int bh = blockIdx.z;
  const u16* Qb = Q + (size_t)bh * 65536;
  const u16* Kb = Kp + (size_t)bh * 65536;
  __shared__ __align__(16) u16 sQ[128 * 64];
  __shared__ __align__(16) u16 sK[128 * 64];
  const int tid = threadIdx.x;
  const int m0 = blockIdx.x * 128, n0 = blockIdx.y * 128;
  {
    int row = tid >> 1, half = tid & 1;
    const u16* gq = &Qb[(size_t)(m0 + row) * 64 + half * 32];
    const u16* gk = &Kb[(size_t)(n0 + row) * 64 + half * 32];
    int xr = row & 7;
#pragma unroll
    for (int q = 0; q < 4; ++q) {
      int gp = (half * 4 + q) ^ xr;
      *(uint4*)&sQ[row * 64 + gp * 8] = *(const uint4*)&gq[q * 8];
      *(uint4*)&sK[row * 64 + gp * 8] = *(const uint4*)&gk[q * 8];
    }
  }
  __syncthreads();
  const int lane = tid & 63, wid = tid >> 6;
  const int wr = wid >> 1, wc = wid & 1;
  const int l15 = lane & 15, l4 = lane >> 4;
  f32x4 acc[4][4] = {};
  bf16x8 af[4][2], bf[4][2];
#pragma unroll
  for (int mr = 0; mr < 4; ++mr) {
    int row = wr * 64 + mr * 16 + l15;
#pragma unroll
    for (int ks = 0; ks < 2; ++ks)
      af[mr][ks] = *(bf16x8*)&sQ[row * 64 + ((ks * 4 + l4) ^ (row & 7)) * 8];
  }
#pragma unroll
  for (int nr = 0; nr < 4; ++nr) {
    int row = wc * 64 + nr * 16 + l15;
#pragma unroll
    for (int ks = 0; ks < 2; ++ks)
      bf[nr][ks] = *(bf16x8*)&sK[row * 64 + ((ks * 4 + l4) ^ (row & 7)) * 8];
  }
#pragma unroll
  for (int mr = 0; mr < 4; ++mr)
#pragma unroll
    for (int nr = 0; nr < 4; ++nr)
#pragma unroll
      for (int ks = 0; ks < 2; ++ks)
        acc[mr][nr] = __builtin_amdgcn_mfma_f32_16x16x32_bf16(af[mr][ks], bf[nr][ks],
                                                              acc[mr][nr], 0, 0, 0);
  __syncthreads();
  unsigned char* t8 = (unsigned char*)sQ;  // reuse 16KB as fp8 [128][128]
#pragma unroll
  for (int mr = 0; mr < 4; ++mr) {
    int mloc = wr * 64 + mr * 16 + l4 * 4;
#pragma unroll
    for (int nr = 0; nr < 4; ++nr) {
      int nloc = wc * 64 + nr * 16 + l15;
#pragma unroll
      for (int r = 0; r < 4; ++r)
        t8[(mloc + r) * 128 + nloc] = f2fp8(acc[mr][nr][r]);
    }
  }
  __syncthreads();
  {
    int row = tid >> 1, c0 = (tid & 1) * 64;
    unsigned char* dst = &S8[((size_t)bh << 20) + (size_t)(m0 + row) * 1024 + n0 + c0];
#pragma unroll
    for (int q = 0; q < 4; ++q)
      *(uint4*)&dst[q * 16] = *(uint4*)&t8[row * 128 + c0 + q * 16];
  }
}

// ---------- Kernel 3: conv3x3(heads)+BN+sigmoid+exp, all-fp8 MFMA GEMM ----------
// (unchanged from round 12: transposed C[j][m], u32 P stores)
__global__ __launch_bounds__(256) void k_conv(
    const unsigned char* __restrict__ S8, unsigned char* __restrict__ P8,
    float* __restrict__ D, const float* __restrict__ cw,
    const float* __restrict__ cb, const float* __restrict__ bg,
    const float* __restrict__ bb, const float* __restrict__ bm,
    const float* __restrict__ bv) {
  const int b = blockIdx.x >> 9, ip = blockIdx.x & 511;
  const int i0 = ip * 2;
  __shared__ __align__(16) unsigned char sC[1026 * 40];  // [ci][k], 40B pitch
  __shared__ __align__(8) unsigned char sA[3][16][40];   // weights per tap, fp8
  __shared__ float sRedD[4][16];
  const int tid = threadIdx.x;
  const int lane = tid & 63, wid = tid >> 6;
  const int l15 = lane & 15, l4 = lane >> 4;

  for (int u = tid; u < 1536; u += 256) {
    int tap = u >> 9, rem = u & 511;
    int m = rem >> 5, kk = rem & 31;
    int p = m >> 3, oh = m & 7;
    int ih = kk >> 2, rr = kk & 3;
    int dr = rr - p;
    float v = 0.f;
    if (dr >= 0 && dr < 3) {
      float ah = bg[oh] * rsqrtf(bv[oh] + 1e-5f);
      v = cw[((oh * 8 + ih) * 3 + dr) * 3 + tap] * ah;
    }
    sA[tap][m][kk] = f2fp8(v);
  }
  if (tid < 20) {
    int c = (tid < 10) ? 0 : 1025;
    ((u32*)&sC[c * 40])[tid % 10] = 0;
  }
  {
    const int ihs = tid >> 5;
    const int lc = tid & 31;
    const unsigned char* Sb = S8 + (((size_t)(b * 8 + ihs)) << 20);
    for (int it = 0; it < 8; ++it) {
      int c0 = (lc + it * 32) * 4;
      u32 w[4];
#pragma unroll
      for (int rr = 0; rr < 4; ++rr) {
        int r = i0 - 1 + rr;
        w[rr] = (r >= 0 && r < 1024) ? *(const u32*)&Sb[(size_t)r * 1024 + c0] : 0u;
      }
#pragma unroll
      for (int cc = 0; cc < 4; ++cc) {
        u32 v = ((w[0] >> (8 * cc)) & 0xffu) | (((w[1] >> (8 * cc)) & 0xffu) << 8) |
                (((w[2] >> (8 * cc)) & 0xffu) << 16) |
                (((w[3] >> (8 * cc)) & 0xffu) << 24);
        *(u32*)&sC[(c0 + cc + 1) * 40 + ihs * 4] = v;
      }
    }
  }
  __syncthreads();

  long wfr[3];
#pragma unroll
  for (int tap = 0; tap < 3; ++tap)
    wfr[tap] = *(long*)&sA[tap][l15][l4 * 8];
  const int oh = l15 & 7, p = l15 >> 3;
  const float ah = bg[oh] * rsqrtf(bv[oh] + 1e-5f);
  const float biasm = cb[oh] * ah + bb[oh] - bm[oh] * ah;
  unsigned char* Prow = &P8[((size_t)(b * 8 + oh) << 20) + ((size_t)(i0 + p) << 10)];
  float dsum = 0.f;

  const int jw = wid * 256;
  for (int t = 0; t < 16; ++t) {
    int jbase = jw + t * 16;
    f32x4 acc = {0.f, 0.f, 0.f, 0.f};
#pragma unroll
    for (int tap = 0; tap < 3; ++tap) {
      long sfr = *(long*)&sC[(size_t)(jbase + l15 + tap) * 40 + l4 * 8];
      acc = __builtin_amdgcn_mfma_f32_16x16x32_fp8_fp8(sfr, wfr[tap], acc, 0, 0, 0);
    }
    float e[4];
#pragma unroll
    for (int r = 0; r < 4; ++r) {
      float tt = acc[r] + biasm;
      float sg = 1.f / (1.f + __expf(-tt));
      e[r] = __expf(sg);
    }
    u32 pw = pk4_fp8(e[0], e[1], e[2], e[3]);
    *(u32*)&Prow[jbase + l4 * 4] = pw;
    f32x2 dlo = up2_lo(pw), dhi = up2_hi(pw);
    dsum += (dlo.x + dlo.y) + (dhi.x + dhi.y);
  }
  dsum += __shfl_xor(dsum, 16);
  dsum += __shfl_xor(dsum, 32);
  if (l4 == 0) sRedD[wid][l15] = dsum;
  __syncthreads();
  if (tid < 16) {
    int pp = tid >> 3, ohh = tid & 7;
    D[((size_t)(b * 8 + ohh) << 10) + i0 + pp] =
        sRedD[0][tid] + sRedD[1][tid] + sRedD[2][tid] + sRedD[3][tid];
  }
}

// ---------- Kernel 4: Z = (P @ V) / D per (b,h), fp8 MFMA, LDS-free ----------
// A-frags: direct global b64 from row-major P (lane=row, 8 contiguous k).
// B-frags: direct global b64 from Vt8[bh][d][j] (L2-resident, 64KB/bh).
__global__ __launch_bounds__(256) void k_av(const unsigned char* __restrict__ P8,
                                            const unsigned char* __restrict__ Vt8,
                                            const float* __restrict__ D,
                                            u16* __restrict__ Z) {
  const int bh = blockIdx.y, m0 = blockIdx.x * 128;
  const int b = bh >> 3, h = bh & 7;
  const int tid = threadIdx.x, lane = tid & 63, w = tid >> 6;
  const int l15 = lane & 15, l4 = lane >> 4;
  const unsigned char* Pb = P8 + ((size_t)bh << 20);
  const unsigned char* Vb = Vt8 + ((size_t)bh << 16);
  const int r0 = m0 + w * 32 + l15;
  f32x4 acc[2][4] = {};
  for (int k0 = 0; k0 < 1024; k0 += 64) {
#pragma unroll
    for (int ks = 0; ks < 2; ++ks) {
      const int ko = k0 + ks * 32 + l4 * 8;
      long a0 = *(const long*)&Pb[(size_t)r0 * 1024 + ko];
      long a1 = *(const long*)&Pb[(size_t)(r0 + 16) * 1024 + ko];
      long bv[4];
#pragma unroll
      for (int nr = 0; nr < 4; ++nr)
        bv[nr] = *(const long*)&Vb[(size_t)(nr * 16 + l15) * 1024 + ko];
#pragma unroll
      for (int nr = 0; nr < 4; ++nr) {
        acc[0][nr] = __builtin_amdgcn_mfma_f32_16x16x32_fp8_fp8(a0, bv[nr],
                                                                acc[0][nr], 0, 0, 0);
        acc[1][nr] = __builtin_amdgcn_mfma_f32_16x16x32_fp8_fp8(a1, bv[nr],
                                                                acc[1][nr], 0, 0, 0);
      }
    }
  }
#pragma unroll
  for (int mr = 0; mr < 2; ++mr) {
    int mbase = m0 + w * 32 + mr * 16 + l4 * 4;
    float dv[4];
#pragma unroll
    for (int r = 0; r < 4; ++r) dv[r] = 1.f / D[((size_t)bh << 10) + mbase + r];
#pragma unroll
    for (int nr = 0; nr < 4; ++nr) {
      int d = nr * 16 + l15;
#pragma unroll
      for (int r = 0; r < 4; ++r)
        Z[((size_t)(b * 1024 + mbase + r)) * 512 + h * 64 + d] =
            f2bf(acc[mr][nr][r] * dv[r]);
    }
  }
}

// ---------- Kernel 5: out = Z @ W^T + b + x, bf16 MFMA. M=8192,N=512,K=512 ----------
__global__ __launch_bounds__(256) void k_proj(const u16* __restrict__ Z,
                                              const float* __restrict__ w,
                                              const float* __restrict__ bias,
                                              const float* __restrict__ xin,
                                              float* __restrict__ out) {
  __shared__ __align__(16) u16 sA[128 * 64];
  __shared__ __align__(16) u16 sB[128 * 64];
  const int tid = threadIdx.x;
  const int m0 = blockIdx.x * 128, n0 = blockIdx.y * 128;
  const int lane = tid & 63, wid = tid >> 6;
  const int wr = wid >> 1, wc = wid & 1;
  const int l15 = lane & 15, l4 = lane >> 4;
  const int row = tid >> 1, half = tid & 1, xr = row & 7;
  f32x4 acc[4][4] = {};
  for (int k0 = 0; k0 < 512; k0 += 64) {
    __syncthreads();
    {
      const u16* gz = &Z[(size_t)(m0 + row) * 512 + k0 + half * 32];
      const float* gb = &w[(size_t)(n0 + row) * 512 + k0 + half * 32];
#pragma unroll
      for (int q = 0; q < 4; ++q) {
        int gp = (half * 4 + q) ^ xr;
        *(uint4*)&sA[row * 64 + gp * 8] = *(const uint4*)&gz[q * 8];
        float4 b0 = *(const float4*)&gb[q * 8];
        float4 b1 = *(const float4*)&gb[q * 8 + 4];
        uint4 pb;
        pb.x = cvtpk_bf16(b0.x, b0.y); pb.y = cvtpk_bf16(b0.z, b0.w);
        pb.z = cvtpk_bf16(b1.x, b1.y); pb.w = cvtpk_bf16(b1.z, b1.w);
        *(uint4*)&sB[row * 64 + gp * 8] = pb;
      }
    }
    __syncthreads();
#pragma unroll
    for (int ks = 0; ks < 2; ++ks) {
      bf16x8 af[4], bfr[4];
#pragma unroll
      for (int mr = 0; mr < 4; ++mr) {
        int rr = wr * 64 + mr * 16 + l15;
        af[mr] = *(bf16x8*)&sA[rr * 64 + ((ks * 4 + l4) ^ (rr & 7)) * 8];
      }
#pragma unroll
      for (int nr = 0; nr < 4; ++nr) {
        int rr = wc * 64 + nr * 16 + l15;
        bfr[nr] = *(bf16x8*)&sB[rr * 64 + ((ks * 4 + l4) ^ (rr & 7)) * 8];
      }
#pragma unroll
      for (int mr = 0; mr < 4; ++mr)
#pragma unroll
        for (int nr = 0; nr < 4; ++nr)
          acc[mr][nr] = __builtin_amdgcn_mfma_f32_16x16x32_bf16(af[mr], bfr[nr],
                                                                acc[mr][nr], 0, 0, 0);
    }
  }
#pragma unroll
  for (int nr = 0; nr < 4; ++nr) {
    int nn = n0 + wc * 64 + nr * 16 + l15;
    float bv2 = bias[nn];
#pragma unroll
    for (int mr = 0; mr < 4; ++mr) {
      int mb = m0 + wr * 64 + mr * 16 + l4 * 4;
#pragma unroll
      for (int r = 0; r < 4; ++r) {
        size_t o = (size_t)(mb + r) * 512 + nn;
        out[o] = acc[mr][nr][r] + bv2 + xin[o];
      }
    }
  }
}

extern "C" void kernel_launch(void* const* d_in, const int* in_sizes, int n_in,
                              void* d_out, int out_size, void* d_ws, size_t ws_size,
                              hipStream_t stream) {
  const size_t need = 160ull << 20;
  if (ws_size < need) return;  // clean diagnostic failure instead of GPU fault

  const float* x      = (const float*)d_in[0];
  const float* qkv_w  = (const float*)d_in[1];
  const float* proj_w = (const float*)d_in[2];
  const float* proj_b = (const float*)d_in[3];
  const float* conv_w = (const float*)d_in[4];
  const float* conv_b = (const float*)d_in[5];
  const float* bn_g   = (const float*)d_in[6];
  const float* bn_b   = (const float*)d_in[7];
  const float* bn_m   = (const float*)d_in[8];
  const float* bn_v   = (const float*)d_in[9];
  float* out = (float*)d_out;

  char* W = (char*)d_ws;
  u16* Wq = (u16*)W;                       // Q bf16 8MB; dead after k_qk
  float* Dbuf = (float*)W;                 // D f32 256KB, overlays Q region
  u16* Wk = (u16*)(W + (8ull << 20));
  unsigned char* Vt8 = (unsigned char*)(W + (16ull << 20));  // V^T fp8 4MB
  u16* Wz = (u16*)(W + (24ull << 20));
  unsigned char* S8 = (unsigned char*)(W + (32ull << 20));  // 64MB
  unsigned char* P8 = (unsigned char*)(W + (96ull << 20));  // 64MB

  k_qkv<<<dim3(64, 12), 256, 0, stream>>>(x, qkv_w, Wq, Wk, Vt8);
  k_qk<<<dim3(8, 8, 64), 256, 0, stream>>>(Wq, Wk, S8);
  k_conv<<<dim3(4096), 256, 0, stream>>>(S8, P8, Dbuf, conv_w, conv_b, bn_g, bn_b,
                                         bn_m, bn_v);
  k_av<<<dim3(8, 64), 256, 0, stream>>>(P8, Vt8, Dbuf, Wz);
  k_proj<<<dim3(64, 4), 256, 0, stream>>>(Wz, proj_w, proj_b, x, out);
}

// Round 15
// 216.239 us; speedup vs baseline: 1.1081x; 1.1081x over previous
//
#include <hip/hip_runtime.h>

// GuidedAttention on MI355X, round 15: full revert to round-12 (215us
// validated; round-13/14's k_av-LDS-free + k_qkv-restructure regressed to 240
// via uncoalesced direct loads) + ONE fix: k_conv staging writes rotated by
// (lane>>2) so the 64 lanes hit 32 distinct banks (was 4 banks / 8-way).
// b=8, n=1024, c=512, H=8, hd=64.
// ws layout (160 MB): [Q bf16 8MB | D f32 256KB overlaid after k_qk]
//                     [K bf16 8MB][V bf16 8MB][Z bf16 8MB]
//                     [S fp8 64MB][P fp8 64MB]

#define DINL __device__ __forceinline__
typedef unsigned short u16;
typedef unsigned int u32;
typedef unsigned long long u64;
typedef short bf16x8 __attribute__((ext_vector_type(8)));
typedef float f32x4 __attribute__((ext_vector_type(4)));
typedef float f32x2 __attribute__((ext_vector_type(2)));

DINL u16 f2bf(float f) {
  u32 u = __float_as_uint(f);
  u += 0x7fffu + ((u >> 16) & 1u);
  return (u16)(u >> 16);
}
DINL float bflo(u32 u) { return __uint_as_float(u << 16); }
DINL float bfhi(u32 u) { return __uint_as_float(u & 0xffff0000u); }
DINL u32 cvtpk_bf16(float lo, float hi) {
  u32 r;
  asm("v_cvt_pk_bf16_f32 %0, %1, %2" : "=v"(r) : "v"(lo), "v"(hi));
  return r;
}
DINL u32 pk4_fp8(float a, float b, float c, float d) {
  u32 r = 0;
  r = (u32)__builtin_amdgcn_cvt_pk_fp8_f32(a, b, (int)r, false);
  r = (u32)__builtin_amdgcn_cvt_pk_fp8_f32(c, d, (int)r, true);
  return r;
}
DINL f32x2 up2_lo(u32 w) { return __builtin_amdgcn_cvt_pk_f32_fp8((int)w, false); }
DINL f32x2 up2_hi(u32 w) { return __builtin_amdgcn_cvt_pk_f32_fp8((int)w, true); }
DINL unsigned char f2fp8(float v) {
  return (unsigned char)((u32)__builtin_amdgcn_cvt_pk_fp8_f32(v, v, 0, false) & 0xffu);
}

// ---------- Kernel 1: QKV proj, bf16 MFMA. M=8192, N=1536, K=512 ----------
__global__ __launch_bounds__(256) void k_qkv(const float* __restrict__ x,
                                             const float* __restrict__ w,
                                             u16* __restrict__ Q,
                                             u16* __restrict__ K,
                                             u16* __restrict__ V) {
  __shared__ __align__(16) u16 sA[128 * 64];
  __shared__ __align__(16) u16 sB[128 * 64];
  const int tid = threadIdx.x;
  const int m0 = blockIdx.x * 128, n0 = blockIdx.y * 128;
  const int lane = tid & 63, wid = tid >> 6;
  const int wr = wid >> 1, wc = wid & 1;
  const int l15 = lane & 15, l4 = lane >> 4;
  const int row = tid >> 1, half = tid & 1, xr = row & 7;
  f32x4 acc[4][4] = {};
  for (int k0 = 0; k0 < 512; k0 += 64) {
    __syncthreads();
    {
      const float* ga = &x[(size_t)(m0 + row) * 512 + k0 + half * 32];
      const float* gb = &w[(size_t)(n0 + row) * 512 + k0 + half * 32];
#pragma unroll
      for (int q = 0; q < 4; ++q) {
        int gp = (half * 4 + q) ^ xr;
        float4 a0 = *(const float4*)&ga[q * 8];
        float4 a1 = *(const float4*)&ga[q * 8 + 4];
        uint4 pa;
        pa.x = cvtpk_bf16(a0.x, a0.y); pa.y = cvtpk_bf16(a0.z, a0.w);
        pa.z = cvtpk_bf16(a1.x, a1.y); pa.w = cvtpk_bf16(a1.z, a1.w);
        *(uint4*)&sA[row * 64 + gp * 8] = pa;
        float4 b0 = *(const float4*)&gb[q * 8];
        float4 b1 = *(const float4*)&gb[q * 8 + 4];
        uint4 pb;
        pb.x = cvtpk_bf16(b0.x, b0.y); pb.y = cvtpk_bf16(b0.z, b0.w);
        pb.z = cvtpk_bf16(b1.x, b1.y); pb.w = cvtpk_bf16(b1.z, b1.w);
        *(uint4*)&sB[row * 64 + gp * 8] = pb;
      }
    }
    __syncthreads();
#pragma unroll
    for (int ks = 0; ks < 2; ++ks) {
      bf16x8 af[4], bfr[4];
#pragma unroll
      for (int mr = 0; mr < 4; ++mr) {
        int rr = wr * 64 + mr * 16 + l15;
        af[mr] = *(bf16x8*)&sA[rr * 64 + ((ks * 4 + l4) ^ (rr & 7)) * 8];
      }
#pragma unroll
      for (int nr = 0; nr < 4; ++nr) {
        int rr = wc * 64 + nr * 16 + l15;
        bfr[nr] = *(bf16x8*)&sB[rr * 64 + ((ks * 4 + l4) ^ (rr & 7)) * 8];
      }
#pragma unroll
      for (int mr = 0; mr < 4; ++mr)
#pragma unroll
        for (int nr = 0; nr < 4; ++nr)
          acc[mr][nr] = __builtin_amdgcn_mfma_f32_16x16x32_bf16(af[mr], bfr[nr],
                                                                acc[mr][nr], 0, 0, 0);
    }
  }
#pragma unroll
  for (int nr = 0; nr < 4; ++nr) {
    int nn = n0 + wc * 64 + nr * 16 + l15;
    int which = nn >> 9, co = nn & 511;
    int head = co >> 6, d = co & 63;
    u16* dst = (which == 0) ? Q : (which == 1) ? K : V;
    float sc = (which == 0) ? 0.125f : 1.f;
#pragma unroll
    for (int mr = 0; mr < 4; ++mr) {
      int mb = m0 + wr * 64 + mr * 16 + l4 * 4;
#pragma unroll
      for (int r = 0; r < 4; ++r) {
        int m = mb + r;
        int bb = m >> 10, ii = m & 1023;
        dst[((((size_t)bb * 8 + head) << 10) + ii) * 64 + d] =
            f2bf(acc[mr][nr][r] * sc);
      }
    }
  }
}

// ---------- Kernel 2: S = Q @ K^T per (b,h), bf16 MFMA, out fp8 ----------
__global__ __launch_bounds__(256) void k_qk(const u16* __restrict__ Q,
                                            const u16* __restrict__ Kp,
                                            unsigned char* __restrict__ S8) {
  const int bh = blockIdx.z;
  const u16* Qb = Q + (size_t)bh * 65536;
  const u16* Kb = Kp + (size_t)bh * 65536;
  __shared__ __align__(16) u16 sQ[128 * 64];
  __shared__ __align__(16) u16 sK[128 * 64];
  const int tid = threadIdx.x;
  const int m0 = blockIdx.x * 128, n0 = blockIdx.y * 128;
  {
    int row = tid >> 1, half = tid & 1;
    const u16* gq = &Qb[(size_t)(m0 + row) * 64 + half * 32];
    const u16* gk = &Kb[(size_t)(n0 + row) * 64 + half * 32];
    int xr = row & 7;
#pragma unroll
    for (int q = 0; q < 4; ++q) {
      int gp = (half * 4 + q) ^ xr;
      *(uint4*)&sQ[row * 64 + gp * 8] = *(const uint4*)&gq[q * 8];
      *(uint4*)&sK[row * 64 + gp * 8] = *(const uint4*)&gk[q * 8];
    }
  }
  __syncthreads();
  const int lane = tid & 63, wid = tid >> 6;
  const int wr = wid >> 1, wc = wid & 1;
  const int l15 = lane & 15, l4 = lane >> 4;
  f32x4 acc[4][4] = {};
  bf16x8 af[4][2], bf[4][2];
#pragma unroll
  for (int mr = 0; mr < 4; ++mr) {
    int row = wr * 64 + mr * 16 + l15;
#pragma unroll
    for (int ks = 0; ks < 2; ++ks)
      af[mr][ks] = *(bf16x8*)&sQ[row * 64 + ((ks * 4 + l4) ^ (row & 7)) * 8];
  }
#pragma unroll
  for (int nr = 0; nr < 4; ++nr) {
    int row = wc * 64 + nr * 16 + l15;
#pragma unroll
    for (int ks = 0; ks < 2; ++ks)
      bf[nr][ks] = *(bf16x8*)&sK[row * 64 + ((ks * 4 + l4) ^ (row & 7)) * 8];
  }
#pragma unroll
  for (int mr = 0; mr < 4; ++mr)
#pragma unroll
    for (int nr = 0; nr < 4; ++nr)
#pragma unroll
      for (int ks = 0; ks < 2; ++ks)
        acc[mr][nr] = __builtin_amdgcn_mfma_f32_16x16x32_bf16(af[mr][ks], bf[nr][ks],
                                                              acc[mr][nr], 0, 0, 0);
  __syncthreads();
  unsigned char* t8 = (unsigned char*)sQ;  // reuse 16KB as fp8 [128][128]
#pragma unroll
  for (int mr = 0; mr < 4; ++mr) {
    int mloc = wr * 64 + mr * 16 + l4 * 4;
#pragma unroll
    for (int nr = 0; nr < 4; ++nr) {
      int nloc = wc * 64 + nr * 16 + l15;
#pragma unroll
      for (int r = 0; r < 4; ++r)
        t8[(mloc + r) * 128 + nloc] = f2fp8(acc[mr][nr][r]);
    }
  }
  __syncthreads();
  {
    int row = tid >> 1, c0 = (tid & 1) * 64;
    unsigned char* dst = &S8[((size_t)bh << 20) + (size_t)(m0 + row) * 1024 + n0 + c0];
#pragma unroll
    for (int q = 0; q < 4; ++q)
      *(uint4*)&dst[q * 16] = *(uint4*)&t8[row * 128 + c0 + q * 16];
  }
}

// ---------- Kernel 3: conv3x3(heads)+BN+sigmoid+exp, all-fp8 MFMA GEMM ----------
// Block per (b, row-pair). TRANSPOSED output C[j][m] (round-12).
// Staging writes rotated by (lane>>2): bank = (8*lc + 10*rot + 10 + ihs) mod 32
// -> 16 even banks (lower half-wave) + 16 odd (upper) = 2 lanes/bank = free.
__global__ __launch_bounds__(256) void k_conv(
    const unsigned char* __restrict__ S8, unsigned char* __restrict__ P8,
    float* __restrict__ D, const float* __restrict__ cw,
    const float* __restrict__ cb, const float* __restrict__ bg,
    const float* __restrict__ bb, const float* __restrict__ bm,
    const float* __restrict__ bv) {
  const int b = blockIdx.x >> 9, ip = blockIdx.x & 511;
  const int i0 = ip * 2;
  __shared__ __align__(16) unsigned char sC[1026 * 40];  // [ci][k], 40B pitch
  __shared__ __align__(8) unsigned char sA[3][16][40];   // weights per tap, fp8
  __shared__ float sRedD[4][16];
  const int tid = threadIdx.x;
  const int lane = tid & 63, wid = tid >> 6;
  const int l15 = lane & 15, l4 = lane >> 4;

  for (int u = tid; u < 1536; u += 256) {
    int tap = u >> 9, rem = u & 511;
    int m = rem >> 5, kk = rem & 31;
    int p = m >> 3, oh = m & 7;
    int ih = kk >> 2, rr = kk & 3;
    int dr = rr - p;
    float v = 0.f;
    if (dr >= 0 && dr < 3) {
      float ah = bg[oh] * rsqrtf(bv[oh] + 1e-5f);
      v = cw[((oh * 8 + ih) * 3 + dr) * 3 + tap] * ah;
    }
    sA[tap][m][kk] = f2fp8(v);
  }
  if (tid < 20) {
    int c = (tid < 10) ? 0 : 1025;
    ((u32*)&sC[c * 40])[tid % 10] = 0;
  }
  // Stage S col-major: u32 loads + in-lane 4x4 byte transpose; write order
  // rotated by (lc>>2) for conflict-free banks.
  {
    const int ihs = tid >> 5;
    const int lc = tid & 31;
    const int rbase = lc >> 2;
    const unsigned char* Sb = S8 + (((size_t)(b * 8 + ihs)) << 20);
    for (int it = 0; it < 8; ++it) {
      int c0 = (lc + it * 32) * 4;
      u32 w[4];
#pragma unroll
      for (int rr = 0; rr < 4; ++rr) {
        int r = i0 - 1 + rr;
        w[rr] = (r >= 0 && r < 1024) ? *(const u32*)&Sb[(size_t)r * 1024 + c0] : 0u;
      }
#pragma unroll
      for (int cc = 0; cc < 4; ++cc) {
        int rot = (cc + rbase) & 3;
        u32 v = ((w[0] >> (8 * rot)) & 0xffu) | (((w[1] >> (8 * rot)) & 0xffu) << 8) |
                (((w[2] >> (8 * rot)) & 0xffu) << 16) |
                (((w[3] >> (8 * rot)) & 0xffu) << 24);
        *(u32*)&sC[(c0 + rot + 1) * 40 + ihs * 4] = v;
      }
    }
  }
  __syncthreads();

  long wfr[3];
#pragma unroll
  for (int tap = 0; tap < 3; ++tap)
    wfr[tap] = *(long*)&sA[tap][l15][l4 * 8];
  const int oh = l15 & 7, p = l15 >> 3;
  const float ah = bg[oh] * rsqrtf(bv[oh] + 1e-5f);
  const float biasm = cb[oh] * ah + bb[oh] - bm[oh] * ah;
  unsigned char* Prow = &P8[((size_t)(b * 8 + oh) << 20) + ((size_t)(i0 + p) << 10)];
  float dsum = 0.f;

  const int jw = wid * 256;
  for (int t = 0; t < 16; ++t) {
    int jbase = jw + t * 16;
    f32x4 acc = {0.f, 0.f, 0.f, 0.f};
#pragma unroll
    for (int tap = 0; tap < 3; ++tap) {
      long sfr = *(long*)&sC[(size_t)(jbase + l15 + tap) * 40 + l4 * 8];
      acc = __builtin_amdgcn_mfma_f32_16x16x32_fp8_fp8(sfr, wfr[tap], acc, 0, 0, 0);
    }
    float e[4];
#pragma unroll
    for (int r = 0; r < 4; ++r) {
      float tt = acc[r] + biasm;
      float sg = 1.f / (1.f + __expf(-tt));
      e[r] = __expf(sg);  // softmax numerator; sg in (0,1) so no max needed
    }
    u32 pw = pk4_fp8(e[0], e[1], e[2], e[3]);
    *(u32*)&Prow[jbase + l4 * 4] = pw;
    // denominator from QUANTIZED numerators for exact normalization
    f32x2 dlo = up2_lo(pw), dhi = up2_hi(pw);
    dsum += (dlo.x + dlo.y) + (dhi.x + dhi.y);
  }
  dsum += __shfl_xor(dsum, 16);
  dsum += __shfl_xor(dsum, 32);
  if (l4 == 0) sRedD[wid][l15] = dsum;
  __syncthreads();
  if (tid < 16) {
    int pp = tid >> 3, ohh = tid & 7;
    D[((size_t)(b * 8 + ohh) << 10) + i0 + pp] =
        sRedD[0][tid] + sRedD[1][tid] + sRedD[2][tid] + sRedD[3][tid];
  }
}

// ---------- Kernel 4: Z = (P @ V) / D per (b,h), fp8 MFMA ----------
__global__ __launch_bounds__(256) void k_av(const unsigned char* __restrict__ P8,
                                            const u16* __restrict__ V,
                                            const float* __restrict__ D,
                                            u16* __restrict__ Z) {
  const int bh = blockIdx.y, m0 = blockIdx.x * 128;
  const int b = bh >> 3, h = bh & 7;
  __shared__ __align__(16) unsigned char sA8[128 * 64];
  __shared__ __align__(16) unsigned char sVt[64 * 64];
  const int tid = threadIdx.x, lane = tid & 63, wid = tid >> 6;
  const int wr = wid >> 1, wc = wid & 1, l15 = lane & 15, l4 = lane >> 4;
  f32x4 acc[4][2] = {};
  for (int k0 = 0; k0 < 1024; k0 += 64) {
    __syncthreads();
    {  // stage A (P fp8), swizzled
      int row = tid >> 1, c0 = (tid & 1) * 32;
      const unsigned char* src =
          &P8[((size_t)bh << 20) + (size_t)(m0 + row) * 1024 + k0 + c0];
      uint4 a0 = *(const uint4*)src, a1 = *(const uint4*)(src + 16);
      u64 ul[4];
      ul[0] = (u64)a0.x | ((u64)a0.y << 32);
      ul[1] = (u64)a0.z | ((u64)a0.w << 32);
      ul[2] = (u64)a1.x | ((u64)a1.y << 32);
      ul[3] = (u64)a1.z | ((u64)a1.w << 32);
      int xr = row & 7, gb = c0 >> 3;
#pragma unroll
      for (int t = 0; t < 4; ++t)
        *(u64*)&sA8[row * 64 + ((gb + t) ^ xr) * 8] = ul[t];
    }
    {  // stage V^T as fp8, swizzled
      int j = tid >> 2, d0 = (tid & 3) * 16;
      const u16* src = &V[((size_t)bh << 16) + (size_t)(k0 + j) * 64 + d0];
      uint4 v0 = *(const uint4*)src, v1 = *(const uint4*)(src + 16);
      u32 wv[8] = {v0.x, v0.y, v0.z, v0.w, v1.x, v1.y, v1.z, v1.w};
#pragma unroll
      for (int t = 0; t < 8; ++t) {
        u32 p = (u32)__builtin_amdgcn_cvt_pk_fp8_f32(bflo(wv[t]), bfhi(wv[t]), 0, false);
        int da = d0 + t * 2, db = da + 1;
        sVt[da * 64 + (((j >> 3) ^ (da & 7)) << 3) + (j & 7)] = (unsigned char)(p & 0xff);
        sVt[db * 64 + (((j >> 3) ^ (db & 7)) << 3) + (j & 7)] = (unsigned char)((p >> 8) & 0xff);
      }
    }
    __syncthreads();
    long bfr[2][2];
#pragma unroll
    for (int nr = 0; nr < 2; ++nr) {
      int row = wc * 32 + nr * 16 + l15;
#pragma unroll
      for (int ks = 0; ks < 2; ++ks)
        bfr[nr][ks] = *(long*)&sVt[row * 64 + (((ks * 4 + l4) ^ (row & 7)) << 3)];
    }
#pragma unroll
    for (int mr = 0; mr < 4; ++mr) {
      int row = wr * 64 + mr * 16 + l15;
      long afr[2];
#pragma unroll
      for (int ks = 0; ks < 2; ++ks)
        afr[ks] = *(long*)&sA8[row * 64 + (((ks * 4 + l4) ^ (row & 7)) << 3)];
#pragma unroll
      for (int nr = 0; nr < 2; ++nr)
#pragma unroll
        for (int ks = 0; ks < 2; ++ks)
          acc[mr][nr] = __builtin_amdgcn_mfma_f32_16x16x32_fp8_fp8(afr[ks], bfr[nr][ks],
                                                                   acc[mr][nr], 0, 0, 0);
    }
  }
#pragma unroll
  for (int mr = 0; mr < 4; ++mr) {
    int mbase = m0 + wr * 64 + mr * 16 + l4 * 4;
    float dv[4];
#pragma unroll
    for (int r = 0; r < 4; ++r) dv[r] = 1.f / D[((size_t)bh << 10) + mbase + r];
#pragma unroll
    for (int nr = 0; nr < 2; ++nr) {
      int d = wc * 32 + nr * 16 + l15;
#pragma unroll
      for (int r = 0; r < 4; ++r)
        Z[((size_t)(b * 1024 + mbase + r)) * 512 + h * 64 + d] =
            f2bf(acc[mr][nr][r] * dv[r]);
    }
  }
}

// ---------- Kernel 5: out = Z @ W^T + b + x, bf16 MFMA. M=8192,N=512,K=512 ----------
__global__ __launch_bounds__(256) void k_proj(const u16* __restrict__ Z,
                                              const float* __restrict__ w,
                                              const float* __restrict__ bias,
                                              const float* __restrict__ xin,
                                              float* __restrict__ out) {
  __shared__ __align__(16) u16 sA[128 * 64];
  __shared__ __align__(16) u16 sB[128 * 64];
  const int tid = threadIdx.x;
  const int m0 = blockIdx.x * 128, n0 = blockIdx.y * 128;
  const int lane = tid & 63, wid = tid >> 6;
  const int wr = wid >> 1, wc = wid & 1;
  const int l15 = lane & 15, l4 = lane >> 4;
  const int row = tid >> 1, half = tid & 1, xr = row & 7;
  f32x4 acc[4][4] = {};
  for (int k0 = 0; k0 < 512; k0 += 64) {
    __syncthreads();
    {
      const u16* gz = &Z[(size_t)(m0 + row) * 512 + k0 + half * 32];
      const float* gb = &w[(size_t)(n0 + row) * 512 + k0 + half * 32];
#pragma unroll
      for (int q = 0; q < 4; ++q) {
        int gp = (half * 4 + q) ^ xr;
        *(uint4*)&sA[row * 64 + gp * 8] = *(const uint4*)&gz[q * 8];
        float4 b0 = *(const float4*)&gb[q * 8];
        float4 b1 = *(const float4*)&gb[q * 8 + 4];
        uint4 pb;
        pb.x = cvtpk_bf16(b0.x, b0.y); pb.y = cvtpk_bf16(b0.z, b0.w);
        pb.z = cvtpk_bf16(b1.x, b1.y); pb.w = cvtpk_bf16(b1.z, b1.w);
        *(uint4*)&sB[row * 64 + gp * 8] = pb;
      }
    }
    __syncthreads();
#pragma unroll
    for (int ks = 0; ks < 2; ++ks) {
      bf16x8 af[4], bfr[4];
#pragma unroll
      for (int mr = 0; mr < 4; ++mr) {
        int rr = wr * 64 + mr * 16 + l15;
        af[mr] = *(bf16x8*)&sA[rr * 64 + ((ks * 4 + l4) ^ (rr & 7)) * 8];
      }
#pragma unroll
      for (int nr = 0; nr < 4; ++nr) {
        int rr = wc * 64 + nr * 16 + l15;
        bfr[nr] = *(bf16x8*)&sB[rr * 64 + ((ks * 4 + l4) ^ (rr & 7)) * 8];
      }
#pragma unroll
      for (int mr = 0; mr < 4; ++mr)
#pragma unroll
        for (int nr = 0; nr < 4; ++nr)
          acc[mr][nr] = __builtin_amdgcn_mfma_f32_16x16x32_bf16(af[mr], bfr[nr],
                                                                acc[mr][nr], 0, 0, 0);
    }
  }
#pragma unroll
  for (int nr = 0; nr < 4; ++nr) {
    int nn = n0 + wc * 64 + nr * 16 + l15;
    float bv2 = bias[nn];
#pragma unroll
    for (int mr = 0; mr < 4; ++mr) {
      int mb = m0 + wr * 64 + mr * 16 + l4 * 4;
#pragma unroll
      for (int r = 0; r < 4; ++r) {
        size_t o = (size_t)(mb + r) * 512 + nn;
        out[o] = acc[mr][nr][r] + bv2 + xin[o];
      }
    }
  }
}

extern "C" void kernel_launch(void* const* d_in, const int* in_sizes, int n_in,
                              void* d_out, int out_size, void* d_ws, size_t ws_size,
                              hipStream_t stream) {
  const size_t need = 160ull << 20;
  if (ws_size < need) return;  // clean diagnostic failure instead of GPU fault

  const float* x      = (const float*)d_in[0];
  const float* qkv_w  = (const float*)d_in[1];
  const float* proj_w = (const float*)d_in[2];
  const float* proj_b = (const float*)d_in[3];
  const float* conv_w = (const float*)d_in[4];
  const float* conv_b = (const float*)d_in[5];
  const float* bn_g   = (const float*)d_in[6];
  const float* bn_b   = (const float*)d_in[7];
  const float* bn_m   = (const float*)d_in[8];
  const float* bn_v   = (const float*)d_in[9];
  float* out = (float*)d_out;

  char* W = (char*)d_ws;
  u16* Wq = (u16*)W;                       // Q bf16 8MB; dead after k_qk
  float* Dbuf = (float*)W;                 // D f32 256KB, overlays Q region
  u16* Wk = (u16*)(W + (8ull << 20));
  u16* Wv = (u16*)(W + (16ull << 20));
  u16* Wz = (u16*)(W + (24ull << 20));
  unsigned char* S8 = (unsigned char*)(W + (32ull << 20));  // 64MB
  unsigned char* P8 = (unsigned char*)(W + (96ull << 20));  // 64MB

  k_qkv<<<dim3(64, 12), 256, 0, stream>>>(x, qkv_w, Wq, Wk, Wv);
  k_qk<<<dim3(8, 8, 64), 256, 0, stream>>>(Wq, Wk, S8);
  k_conv<<<dim3(4096), 256, 0, stream>>>(S8, P8, Dbuf, conv_w, conv_b, bn_g, bn_b,
                                         bn_m, bn_v);
  k_av<<<dim3(8, 64), 256, 0, stream>>>(P8, Wv, Dbuf, Wz);
  k_proj<<<dim3(64, 4), 256, 0, stream>>>(Wz, proj_w, proj_b, x, out);
}

// Round 16
// 215.906 us; speedup vs baseline: 1.1098x; 1.0015x over previous
//
#include <hip/hip_runtime.h>

// GuidedAttention on MI355X, round 16: round-15 base (216us) with k_conv
// j-split: block = (b, i0-pair, j-half of 512 cols). LDS 43.5->22.8KB (7
// blocks/CU vs 3), per-thread work halved, grid 4096->8192. Denominator
// becomes two deterministic partials Dbuf[jh][bh][i]; k_av uses 1/(D0+D1).
// dsum now sums unquantized e[] (skips fp8 re-decode; error ~0.06%).
// k_qkv/k_qk/k_av(+D0+D1)/k_proj otherwise unchanged.
// ws layout (160 MB): [Q bf16 8MB | Dbuf f32 512KB overlaid after k_qk]
//                     [K bf16 8MB][V bf16 8MB][Z bf16 8MB]
//                     [S fp8 64MB][P fp8 64MB]

#define DINL __device__ __forceinline__
typedef unsigned short u16;
typedef unsigned int u32;
typedef unsigned long long u64;
typedef short bf16x8 __attribute__((ext_vector_type(8)));
typedef float f32x4 __attribute__((ext_vector_type(4)));
typedef float f32x2 __attribute__((ext_vector_type(2)));

DINL u16 f2bf(float f) {
  u32 u = __float_as_uint(f);
  u += 0x7fffu + ((u >> 16) & 1u);
  return (u16)(u >> 16);
}
DINL float bflo(u32 u) { return __uint_as_float(u << 16); }
DINL float bfhi(u32 u) { return __uint_as_float(u & 0xffff0000u); }
DINL u32 cvtpk_bf16(float lo, float hi) {
  u32 r;
  asm("v_cvt_pk_bf16_f32 %0, %1, %2" : "=v"(r) : "v"(lo), "v"(hi));
  return r;
}
DINL u32 pk4_fp8(float a, float b, float c, float d) {
  u32 r = 0;
  r = (u32)__builtin_amdgcn_cvt_pk_fp8_f32(a, b, (int)r, false);
  r = (u32)__builtin_amdgcn_cvt_pk_fp8_f32(c, d, (int)r, true);
  return r;
}
DINL f32x2 up2_lo(u32 w) { return __builtin_amdgcn_cvt_pk_f32_fp8((int)w, false); }
DINL unsigned char f2fp8(float v) {
  return (unsigned char)((u32)__builtin_amdgcn_cvt_pk_fp8_f32(v, v, 0, false) & 0xffu);
}

// ---------- Kernel 1: QKV proj, bf16 MFMA. M=8192, N=1536, K=512 ----------
__global__ __launch_bounds__(256) void k_qkv(const float* __restrict__ x,
                                             const float* __restrict__ w,
                                             u16* __restrict__ Q,
                                             u16* __restrict__ K,
                                             u16* __restrict__ V) {
  __shared__ __align__(16) u16 sA[128 * 64];
  __shared__ __align__(16) u16 sB[128 * 64];
  const int tid = threadIdx.x;
  const int m0 = blockIdx.x * 128, n0 = blockIdx.y * 128;
  const int lane = tid & 63, wid = tid >> 6;
  const int wr = wid >> 1, wc = wid & 1;
  const int l15 = lane & 15, l4 = lane >> 4;
  const int row = tid >> 1, half = tid & 1, xr = row & 7;
  f32x4 acc[4][4] = {};
  for (int k0 = 0; k0 < 512; k0 += 64) {
    __syncthreads();
    {
      const float* ga = &x[(size_t)(m0 + row) * 512 + k0 + half * 32];
      const float* gb = &w[(size_t)(n0 + row) * 512 + k0 + half * 32];
#pragma unroll
      for (int q = 0; q < 4; ++q) {
        int gp = (half * 4 + q) ^ xr;
        float4 a0 = *(const float4*)&ga[q * 8];
        float4 a1 = *(const float4*)&ga[q * 8 + 4];
        uint4 pa;
        pa.x = cvtpk_bf16(a0.x, a0.y); pa.y = cvtpk_bf16(a0.z, a0.w);
        pa.z = cvtpk_bf16(a1.x, a1.y); pa.w = cvtpk_bf16(a1.z, a1.w);
        *(uint4*)&sA[row * 64 + gp * 8] = pa;
        float4 b0 = *(const float4*)&gb[q * 8];
        float4 b1 = *(const float4*)&gb[q * 8 + 4];
        uint4 pb;
        pb.x = cvtpk_bf16(b0.x, b0.y); pb.y = cvtpk_bf16(b0.z, b0.w);
        pb.z = cvtpk_bf16(b1.x, b1.y); pb.w = cvtpk_bf16(b1.z, b1.w);
        *(uint4*)&sB[row * 64 + gp * 8] = pb;
      }
    }
    __syncthreads();
#pragma unroll
    for (int ks = 0; ks < 2; ++ks) {
      bf16x8 af[4], bfr[4];
#pragma unroll
      for (int mr = 0; mr < 4; ++mr) {
        int rr = wr * 64 + mr * 16 + l15;
        af[mr] = *(bf16x8*)&sA[rr * 64 + ((ks * 4 + l4) ^ (rr & 7)) * 8];
      }
#pragma unroll
      for (int nr = 0; nr < 4; ++nr) {
        int rr = wc * 64 + nr * 16 + l15;
        bfr[nr] = *(bf16x8*)&sB[rr * 64 + ((ks * 4 + l4) ^ (rr & 7)) * 8];
      }
#pragma unroll
      for (int mr = 0; mr < 4; ++mr)
#pragma unroll
        for (int nr = 0; nr < 4; ++nr)
          acc[mr][nr] = __builtin_amdgcn_mfma_f32_16x16x32_bf16(af[mr], bfr[nr],
                                                                acc[mr][nr], 0, 0, 0);
    }
  }
#pragma unroll
  for (int nr = 0; nr < 4; ++nr) {
    int nn = n0 + wc * 64 + nr * 16 + l15;
    int which = nn >> 9, co = nn & 511;
    int head = co >> 6, d = co & 63;
    u16* dst = (which == 0) ? Q : (which == 1) ? K : V;
    float sc = (which == 0) ? 0.125f : 1.f;
#pragma unroll
    for (int mr = 0; mr < 4; ++mr) {
      int mb = m0 + wr * 64 + mr * 16 + l4 * 4;
#pragma unroll
      for (int r = 0; r < 4; ++r) {
        int m = mb + r;
        int bb = m >> 10, ii = m & 1023;
        dst[((((size_t)bb * 8 + head) << 10) + ii) * 64 + d] =
            f2bf(acc[mr][nr][r] * sc);
      }
    }
  }
}

// ---------- Kernel 2: S = Q @ K^T per (b,h), bf16 MFMA, out fp8 ----------
__global__ __launch_bounds__(256) void k_qk(const u16* __restrict__ Q,
                                            const u16* __restrict__ Kp,
                                            unsigned char* __restrict__ S8) {
  const int bh = blockIdx.z;
  const u16* Qb = Q + (size_t)bh * 65536;
  const u16* Kb = Kp + (size_t)bh * 65536;
  __shared__ __align__(16) u16 sQ[128 * 64];
  __shared__ __align__(16) u16 sK[128 * 64];
  const int tid = threadIdx.x;
  const int m0 = blockIdx.x * 128, n0 = blockIdx.y * 128;
  {
    int row = tid >> 1, half = tid & 1;
    const u16* gq = &Qb[(size_t)(m0 + row) * 64 + half * 32];
    const u16* gk = &Kb[(size_t)(n0 + row) * 64 + half * 32];
    int xr = row & 7;
#pragma unroll
    for (int q = 0; q < 4; ++q) {
      int gp = (half * 4 + q) ^ xr;
      *(uint4*)&sQ[row * 64 + gp * 8] = *(const uint4*)&gq[q * 8];
      *(uint4*)&sK[row * 64 + gp * 8] = *(const uint4*)&gk[q * 8];
    }
  }
  __syncthreads();
  const int lane = tid & 63, wid = tid >> 6;
  const int wr = wid >> 1, wc = wid & 1;
  const int l15 = lane & 15, l4 = lane >> 4;
  f32x4 acc[4][4] = {};
  bf16x8 af[4][2], bf[4][2];
#pragma unroll
  for (int mr = 0; mr < 4; ++mr) {
    int row = wr * 64 + mr * 16 + l15;
#pragma unroll
    for (int ks = 0; ks < 2; ++ks)
      af[mr][ks] = *(bf16x8*)&sQ[row * 64 + ((ks * 4 + l4) ^ (row & 7)) * 8];
  }
#pragma unroll
  for (int nr = 0; nr < 4; ++nr) {
    int row = wc * 64 + nr * 16 + l15;
#pragma unroll
    for (int ks = 0; ks < 2; ++ks)
      bf[nr][ks] = *(bf16x8*)&sK[row * 64 + ((ks * 4 + l4) ^ (row & 7)) * 8];
  }
#pragma unroll
  for (int mr = 0; mr < 4; ++mr)
#pragma unroll
    for (int nr = 0; nr < 4; ++nr)
#pragma unroll
      for (int ks = 0; ks < 2; ++ks)
        acc[mr][nr] = __builtin_amdgcn_mfma_f32_16x16x32_bf16(af[mr][ks], bf[nr][ks],
                                                              acc[mr][nr], 0, 0, 0);
  __syncthreads();
  unsigned char* t8 = (unsigned char*)sQ;  // reuse 16KB as fp8 [128][128]
#pragma unroll
  for (int mr = 0; mr < 4; ++mr) {
    int mloc = wr * 64 + mr * 16 + l4 * 4;
#pragma unroll
    for (int nr = 0; nr < 4; ++nr) {
      int nloc = wc * 64 + nr * 16 + l15;
#pragma unroll
      for (int r = 0; r < 4; ++r)
        t8[(mloc + r) * 128 + nloc] = f2fp8(acc[mr][nr][r]);
    }
  }
  __syncthreads();
  {
    int row = tid >> 1, c0 = (tid & 1) * 64;
    unsigned char* dst = &S8[((size_t)bh << 20) + (size_t)(m0 + row) * 1024 + n0 + c0];
#pragma unroll
    for (int q = 0; q < 4; ++q)
      *(uint4*)&dst[q * 16] = *(uint4*)&t8[row * 128 + c0 + q * 16];
  }
}

// ---------- Kernel 3: conv3x3(heads)+BN+sigmoid+exp, all-fp8 MFMA GEMM ----------
// Block per (b, row-pair, j-half). TRANSPOSED output C[j][m]. LDS 22.8KB.
// Denominator written as partial Dbuf[jh][bh][i] (deterministic, no atomics).
__global__ __launch_bounds__(256) void k_conv(
    const unsigned char* __restrict__ S8, unsigned char* __restrict__ P8,
    float* __restrict__ Dbuf, const float* __restrict__ cw,
    const float* __restrict__ cb, const float* __restrict__ bg,
    const float* __restrict__ bb, const float* __restrict__ bm,
    const float* __restrict__ bv) {
  const int blk = blockIdx.x;
  const int b = blk >> 10;
  const int rem = blk & 1023;
  const int ip = rem >> 1, jh = rem & 1;
  const int i0 = ip * 2, j0 = jh * 512;
  __shared__ __align__(16) unsigned char sC[514 * 40];  // [ci][k], 40B pitch
  __shared__ __align__(8) unsigned char sA[3][16][40];  // weights per tap, fp8
  __shared__ float sRedD[4][16];
  const int tid = threadIdx.x;
  const int lane = tid & 63, wid = tid >> 6;
  const int l15 = lane & 15, l4 = lane >> 4;

  // Build weight matrix fp8 (folded with BN scale). 1536 entries.
  for (int u = tid; u < 1536; u += 256) {
    int tap = u >> 9, rem2 = u & 511;
    int m = rem2 >> 5, kk = rem2 & 31;
    int p = m >> 3, oh = m & 7;
    int ih = kk >> 2, rr = kk & 3;
    int dr = rr - p;
    float v = 0.f;
    if (dr >= 0 && dr < 3) {
      float ah = bg[oh] * rsqrtf(bv[oh] + 1e-5f);
      v = cw[((oh * 8 + ih) * 3 + dr) * 3 + tap] * ah;
    }
    sA[tap][m][kk] = f2fp8(v);
  }
  // Boundary columns ci=0 (global j0-1) and ci=513 (global j0+512).
  if (tid < 16) {
    int side = tid & 1, ih = tid >> 1;
    int g = side ? (j0 + 512) : (j0 - 1);
    u32 v = 0;
    if (g >= 0 && g < 1024) {
      const unsigned char* Sb = S8 + (((size_t)(b * 8 + ih)) << 20);
#pragma unroll
      for (int rr = 0; rr < 4; ++rr) {
        int r = i0 - 1 + rr;
        u32 byte = (r >= 0 && r < 1024) ? (u32)Sb[(size_t)r * 1024 + g] : 0u;
        v |= byte << (8 * rr);
      }
    }
    *(u32*)&sC[(side ? 513 : 0) * 40 + ih * 4] = v;
  }
  // Main staging: 512 cols via u32 loads + in-lane 4x4 byte transpose,
  // write order rotated by (lc>>2) for conflict-free banks (round-15).
  {
    const int ihs = tid >> 5;
    const int lc = tid & 31;
    const int rbase = lc >> 2;
    const unsigned char* Sb = S8 + (((size_t)(b * 8 + ihs)) << 20);
    for (int it = 0; it < 4; ++it) {
      int c0l = (lc + it * 32) * 4;  // local col 0..508
      int c0 = j0 + c0l;
      u32 w[4];
#pragma unroll
      for (int rr = 0; rr < 4; ++rr) {
        int r = i0 - 1 + rr;
        w[rr] = (r >= 0 && r < 1024) ? *(const u32*)&Sb[(size_t)r * 1024 + c0] : 0u;
      }
#pragma unroll
      for (int cc = 0; cc < 4; ++cc) {
        int rot = (cc + rbase) & 3;
        u32 v = ((w[0] >> (8 * rot)) & 0xffu) | (((w[1] >> (8 * rot)) & 0xffu) << 8) |
                (((w[2] >> (8 * rot)) & 0xffu) << 16) |
                (((w[3] >> (8 * rot)) & 0xffu) << 24);
        *(u32*)&sC[(c0l + rot + 1) * 40 + ihs * 4] = v;
      }
    }
  }
  __syncthreads();

  long wfr[3];
#pragma unroll
  for (int tap = 0; tap < 3; ++tap)
    wfr[tap] = *(long*)&sA[tap][l15][l4 * 8];
  const int oh = l15 & 7, p = l15 >> 3;
  const float ah = bg[oh] * rsqrtf(bv[oh] + 1e-5f);
  const float biasm = cb[oh] * ah + bb[oh] - bm[oh] * ah;
  unsigned char* Prow =
      &P8[((size_t)(b * 8 + oh) << 20) + ((size_t)(i0 + p) << 10) + j0];
  float dsum = 0.f;

  const int jw = wid * 128;
  for (int t = 0; t < 8; ++t) {
    int jbase = jw + t * 16;  // local j
    f32x4 acc = {0.f, 0.f, 0.f, 0.f};
#pragma unroll
    for (int tap = 0; tap < 3; ++tap) {
      long sfr = *(long*)&sC[(size_t)(jbase + l15 + tap) * 40 + l4 * 8];
      acc = __builtin_amdgcn_mfma_f32_16x16x32_fp8_fp8(sfr, wfr[tap], acc, 0, 0, 0);
    }
    float e[4];
#pragma unroll
    for (int r = 0; r < 4; ++r) {
      float tt = acc[r] + biasm;
      float sg = 1.f / (1.f + __expf(-tt));
      e[r] = __expf(sg);  // softmax numerator; sg in (0,1) so no max needed
    }
    u32 pw = pk4_fp8(e[0], e[1], e[2], e[3]);
    *(u32*)&Prow[jbase + l4 * 4] = pw;
    dsum += (e[0] + e[1]) + (e[2] + e[3]);
  }
  // Reduce across the 4 lanes sharing m=l15 (l4 = lane bits 4-5).
  dsum += __shfl_xor(dsum, 16);
  dsum += __shfl_xor(dsum, 32);
  if (l4 == 0) sRedD[wid][l15] = dsum;
  __syncthreads();
  if (tid < 16) {
    int pp = tid >> 3, ohh = tid & 7;
    Dbuf[(size_t)jh * 65536 + ((size_t)(b * 8 + ohh) << 10) + i0 + pp] =
        sRedD[0][tid] + sRedD[1][tid] + sRedD[2][tid] + sRedD[3][tid];
  }
}

// ---------- Kernel 4: Z = (P @ V) / (D0+D1) per (b,h), fp8 MFMA ----------
__global__ __launch_bounds__(256) void k_av(const unsigned char* __restrict__ P8,
                                            const u16* __restrict__ V,
                                            const float* __restrict__ Dbuf,
                                            u16* __restrict__ Z) {
  const int bh = blockIdx.y, m0 = blockIdx.x * 128;
  const int b = bh >> 3, h = bh & 7;
  __shared__ __align__(16) unsigned char sA8[128 * 64];
  __shared__ __align__(16) unsigned char sVt[64 * 64];
  const int tid = threadIdx.x, lane = tid & 63, wid = tid >> 6;
  const int wr = wid >> 1, wc = wid & 1, l15 = lane & 15, l4 = lane >> 4;
  f32x4 acc[4][2] = {};
  for (int k0 = 0; k0 < 1024; k0 += 64) {
    __syncthreads();
    {  // stage A (P fp8), swizzled
      int row = tid >> 1, c0 = (tid & 1) * 32;
      const unsigned char* src =
          &P8[((size_t)bh << 20) + (size_t)(m0 + row) * 1024 + k0 + c0];
      uint4 a0 = *(const uint4*)src, a1 = *(const uint4*)(src + 16);
      u64 ul[4];
      ul[0] = (u64)a0.x | ((u64)a0.y << 32);
      ul[1] = (u64)a0.z | ((u64)a0.w << 32);
      ul[2] = (u64)a1.x | ((u64)a1.y << 32);
      ul[3] = (u64)a1.z | ((u64)a1.w << 32);
      int xr = row & 7, gb = c0 >> 3;
#pragma unroll
      for (int t = 0; t < 4; ++t)
        *(u64*)&sA8[row * 64 + ((gb + t) ^ xr) * 8] = ul[t];
    }
    {  // stage V^T as fp8, swizzled
      int j = tid >> 2, d0 = (tid & 3) * 16;
      const u16* src = &V[((size_t)bh << 16) + (size_t)(k0 + j) * 64 + d0];
      uint4 v0 = *(const uint4*)src, v1 = *(const uint4*)(src + 16);
      u32 wv[8] = {v0.x, v0.y, v0.z, v0.w, v1.x, v1.y, v1.z, v1.w};
#pragma unroll
      for (int t = 0; t < 8; ++t) {
        u32 p = (u32)__builtin_amdgcn_cvt_pk_fp8_f32(bflo(wv[t]), bfhi(wv[t]), 0, false);
        int da = d0 + t * 2, db = da + 1;
        sVt[da * 64 + (((j >> 3) ^ (da & 7)) << 3) + (j & 7)] = (unsigned char)(p & 0xff);
        sVt[db * 64 + (((j >> 3) ^ (db & 7)) << 3) + (j & 7)] = (unsigned char)((p >> 8) & 0xff);
      }
    }
    __syncthreads();
    long bfr[2][2];
#pragma unroll
    for (int nr = 0; nr < 2; ++nr) {
      int row = wc * 32 + nr * 16 + l15;
#pragma unroll
      for (int ks = 0; ks < 2; ++ks)
        bfr[nr][ks] = *(long*)&sVt[row * 64 + (((ks * 4 + l4) ^ (row & 7)) << 3)];
    }
#pragma unroll
    for (int mr = 0; mr < 4; ++mr) {
      int row = wr * 64 + mr * 16 + l15;
      long afr[2];
#pragma unroll
      for (int ks = 0; ks < 2; ++ks)
        afr[ks] = *(long*)&sA8[row * 64 + (((ks * 4 + l4) ^ (row & 7)) << 3)];
#pragma unroll
      for (int nr = 0; nr < 2; ++nr)
#pragma unroll
        for (int ks = 0; ks < 2; ++ks)
          acc[mr][nr] = __builtin_amdgcn_mfma_f32_16x16x32_fp8_fp8(afr[ks], bfr[nr][ks],
                                                                   acc[mr][nr], 0, 0, 0);
    }
  }
#pragma unroll
  for (int mr = 0; mr < 4; ++mr) {
    int mbase = m0 + wr * 64 + mr * 16 + l4 * 4;
    float dv[4];
#pragma unroll
    for (int r = 0; r < 4; ++r) {
      size_t di = ((size_t)bh << 10) + mbase + r;
      dv[r] = 1.f / (Dbuf[di] + Dbuf[di + 65536]);
    }
#pragma unroll
    for (int nr = 0; nr < 2; ++nr) {
      int d = wc * 32 + nr * 16 + l15;
#pragma unroll
      for (int r = 0; r < 4; ++r)
        Z[((size_t)(b * 1024 + mbase + r)) * 512 + h * 64 + d] =
            f2bf(acc[mr][nr][r] * dv[r]);
    }
  }
}

// ---------- Kernel 5: out = Z @ W^T + b + x, bf16 MFMA. M=8192,N=512,K=512 ----------
__global__ __launch_bounds__(256) void k_proj(const u16* __restrict__ Z,
                                              const float* __restrict__ w,
                                              const float* __restrict__ bias,
                                              const float* __restrict__ xin,
                                              float* __restrict__ out) {
  __shared__ __align__(16) u16 sA[128 * 64];
  __shared__ __align__(16) u16 sB[128 * 64];
  const int tid = threadIdx.x;
  const int m0 = blockIdx.x * 128, n0 = blockIdx.y * 128;
  const int lane = tid & 63, wid = tid >> 6;
  const int wr = wid >> 1, wc = wid & 1;
  const int l15 = lane & 15, l4 = lane >> 4;
  const int row = tid >> 1, half = tid & 1, xr = row & 7;
  f32x4 acc[4][4] = {};
  for (int k0 = 0; k0 < 512; k0 += 64) {
    __syncthreads();
    {
      const u16* gz = &Z[(size_t)(m0 + row) * 512 + k0 + half * 32];
      const float* gb = &w[(size_t)(n0 + row) * 512 + k0 + half * 32];
#pragma unroll
      for (int q = 0; q < 4; ++q) {
        int gp = (half * 4 + q) ^ xr;
        *(uint4*)&sA[row * 64 + gp * 8] = *(const uint4*)&gz[q * 8];
        float4 b0 = *(const float4*)&gb[q * 8];
        float4 b1 = *(const float4*)&gb[q * 8 + 4];
        uint4 pb;
        pb.x = cvtpk_bf16(b0.x, b0.y); pb.y = cvtpk_bf16(b0.z, b0.w);
        pb.z = cvtpk_bf16(b1.x, b1.y); pb.w = cvtpk_bf16(b1.z, b1.w);
        *(uint4*)&sB[row * 64 + gp * 8] = pb;
      }
    }
    __syncthreads();
#pragma unroll
    for (int ks = 0; ks < 2; ++ks) {
      bf16x8 af[4], bfr[4];
#pragma unroll
      for (int mr = 0; mr < 4; ++mr) {
        int rr = wr * 64 + mr * 16 + l15;
        af[mr] = *(bf16x8*)&sA[rr * 64 + ((ks * 4 + l4) ^ (rr & 7)) * 8];
      }
#pragma unroll
      for (int nr = 0; nr < 4; ++nr) {
        int rr = wc * 64 + nr * 16 + l15;
        bfr[nr] = *(bf16x8*)&sB[rr * 64 + ((ks * 4 + l4) ^ (rr & 7)) * 8];
      }
#pragma unroll
      for (int mr = 0; mr < 4; ++mr)
#pragma unroll
        for (int nr = 0; nr < 4; ++nr)
          acc[mr][nr] = __builtin_amdgcn_mfma_f32_16x16x32_bf16(af[mr], bfr[nr],
                                                                acc[mr][nr], 0, 0, 0);
    }
  }
#pragma unroll
  for (int nr = 0; nr < 4; ++nr) {
    int nn = n0 + wc * 64 + nr * 16 + l15;
    float bv2 = bias[nn];
#pragma unroll
    for (int mr = 0; mr < 4; ++mr) {
      int mb = m0 + wr * 64 + mr * 16 + l4 * 4;
#pragma unroll
      for (int r = 0; r < 4; ++r) {
        size_t o = (size_t)(mb + r) * 512 + nn;
        out[o] = acc[mr][nr][r] + bv2 + xin[o];
      }
    }
  }
}

extern "C" void kernel_launch(void* const* d_in, const int* in_sizes, int n_in,
                              void* d_out, int out_size, void* d_ws, size_t ws_size,
                              hipStream_t stream) {
  const size_t need = 160ull << 20;
  if (ws_size < need) return;  // clean diagnostic failure instead of GPU fault

  const float* x      = (const float*)d_in[0];
  const float* qkv_w  = (const float*)d_in[1];
  const float* proj_w = (const float*)d_in[2];
  const float* proj_b = (const float*)d_in[3];
  const float* conv_w = (const float*)d_in[4];
  const float* conv_b = (const float*)d_in[5];
  const float* bn_g   = (const float*)d_in[6];
  const float* bn_b   = (const float*)d_in[7];
  const float* bn_m   = (const float*)d_in[8];
  const float* bn_v   = (const float*)d_in[9];
  float* out = (float*)d_out;

  char* W = (char*)d_ws;
  u16* Wq = (u16*)W;                       // Q bf16 8MB; dead after k_qk
  float* Dbuf = (float*)W;                 // D f32 2x256KB, overlays Q region
  u16* Wk = (u16*)(W + (8ull << 20));
  u16* Wv = (u16*)(W + (16ull << 20));
  u16* Wz = (u16*)(W + (24ull << 20));
  unsigned char* S8 = (unsigned char*)(W + (32ull << 20));  // 64MB
  unsigned char* P8 = (unsigned char*)(W + (96ull << 20));  // 64MB

  k_qkv<<<dim3(64, 12), 256, 0, stream>>>(x, qkv_w, Wq, Wk, Wv);
  k_qk<<<dim3(8, 8, 64), 256, 0, stream>>>(Wq, Wk, S8);
  k_conv<<<dim3(8192), 256, 0, stream>>>(S8, P8, Dbuf, conv_w, conv_b, bn_g, bn_b,
                                         bn_m, bn_v);
  k_av<<<dim3(8, 64), 256, 0, stream>>>(P8, Wv, Dbuf, Wz);
  k_proj<<<dim3(64, 4), 256, 0, stream>>>(Wz, proj_w, proj_b, x, out);
}

// Round 17
// 215.587 us; speedup vs baseline: 1.1114x; 1.0015x over previous
//
#include <hip/hip_runtime.h>

// GuidedAttention on MI355X, round 17: round-16 base (215.9us) with k_conv
// VALU-diet: (1) 4x4 byte transpose via v_perm_b32 (8 perms vs ~28 shift/or),
// (2) rotate-swizzle dropped (bank conflicts proven timing-neutral r14 vs r15),
// (3) row-bounds hoisted to block-uniform branch, (4) base+offset-immediate
// addressing for staging loads and epilogue ds_reads. All else unchanged.
// ws layout (160 MB): [Q bf16 8MB | Dbuf f32 512KB overlaid after k_qk]
//                     [K bf16 8MB][V bf16 8MB][Z bf16 8MB]
//                     [S fp8 64MB][P fp8 64MB]

#define DINL __device__ __forceinline__
typedef unsigned short u16;
typedef unsigned int u32;
typedef unsigned long long u64;
typedef short bf16x8 __attribute__((ext_vector_type(8)));
typedef float f32x4 __attribute__((ext_vector_type(4)));
typedef float f32x2 __attribute__((ext_vector_type(2)));

DINL u16 f2bf(float f) {
  u32 u = __float_as_uint(f);
  u += 0x7fffu + ((u >> 16) & 1u);
  return (u16)(u >> 16);
}
DINL float bflo(u32 u) { return __uint_as_float(u << 16); }
DINL float bfhi(u32 u) { return __uint_as_float(u & 0xffff0000u); }
DINL u32 cvtpk_bf16(float lo, float hi) {
  u32 r;
  asm("v_cvt_pk_bf16_f32 %0, %1, %2" : "=v"(r) : "v"(lo), "v"(hi));
  return r;
}
DINL u32 pk4_fp8(float a, float b, float c, float d) {
  u32 r = 0;
  r = (u32)__builtin_amdgcn_cvt_pk_fp8_f32(a, b, (int)r, false);
  r = (u32)__builtin_amdgcn_cvt_pk_fp8_f32(c, d, (int)r, true);
  return r;
}
DINL unsigned char f2fp8(float v) {
  return (unsigned char)((u32)__builtin_amdgcn_cvt_pk_fp8_f32(v, v, 0, false) & 0xffu);
}

// ---------- Kernel 1: QKV proj, bf16 MFMA. M=8192, N=1536, K=512 ----------
__global__ __launch_bounds__(256) void k_qkv(const float* __restrict__ x,
                                             const float* __restrict__ w,
                                             u16* __restrict__ Q,
                                             u16* __restrict__ K,
                                             u16* __restrict__ V) {
  __shared__ __align__(16) u16 sA[128 * 64];
  __shared__ __align__(16) u16 sB[128 * 64];
  const int tid = threadIdx.x;
  const int m0 = blockIdx.x * 128, n0 = blockIdx.y * 128;
  const int lane = tid & 63, wid = tid >> 6;
  const int wr = wid >> 1, wc = wid & 1;
  const int l15 = lane & 15, l4 = lane >> 4;
  const int row = tid >> 1, half = tid & 1, xr = row & 7;
  f32x4 acc[4][4] = {};
  for (int k0 = 0; k0 < 512; k0 += 64) {
    __syncthreads();
    {
      const float* ga = &x[(size_t)(m0 + row) * 512 + k0 + half * 32];
      const float* gb = &w[(size_t)(n0 + row) * 512 + k0 + half * 32];
#pragma unroll
      for (int q = 0; q < 4; ++q) {
        int gp = (half * 4 + q) ^ xr;
        float4 a0 = *(const float4*)&ga[q * 8];
        float4 a1 = *(const float4*)&ga[q * 8 + 4];
        uint4 pa;
        pa.x = cvtpk_bf16(a0.x, a0.y); pa.y = cvtpk_bf16(a0.z, a0.w);
        pa.z = cvtpk_bf16(a1.x, a1.y); pa.w = cvtpk_bf16(a1.z, a1.w);
        *(uint4*)&sA[row * 64 + gp * 8] = pa;
        float4 b0 = *(const float4*)&gb[q * 8];
        float4 b1 = *(const float4*)&gb[q * 8 + 4];
        uint4 pb;
        pb.x = cvtpk_bf16(b0.x, b0.y); pb.y = cvtpk_bf16(b0.z, b0.w);
        pb.z = cvtpk_bf16(b1.x, b1.y); pb.w = cvtpk_bf16(b1.z, b1.w);
        *(uint4*)&sB[row * 64 + gp * 8] = pb;
      }
    }
    __syncthreads();
#pragma unroll
    for (int ks = 0; ks < 2; ++ks) {
      bf16x8 af[4], bfr[4];
#pragma unroll
      for (int mr = 0; mr < 4; ++mr) {
        int rr = wr * 64 + mr * 16 + l15;
        af[mr] = *(bf16x8*)&sA[rr * 64 + ((ks * 4 + l4) ^ (rr & 7)) * 8];
      }
#pragma unroll
      for (int nr = 0; nr < 4; ++nr) {
        int rr = wc * 64 + nr * 16 + l15;
        bfr[nr] = *(bf16x8*)&sB[rr * 64 + ((ks * 4 + l4) ^ (rr & 7)) * 8];
      }
#pragma unroll
      for (int mr = 0; mr < 4; ++mr)
#pragma unroll
        for (int nr = 0; nr < 4; ++nr)
          acc[mr][nr] = __builtin_amdgcn_mfma_f32_16x16x32_bf16(af[mr], bfr[nr],
                                                                acc[mr][nr], 0, 0, 0);
    }
  }
#pragma unroll
  for (int nr = 0; nr < 4; ++nr) {
    int nn = n0 + wc * 64 + nr * 16 + l15;
    int which = nn >> 9, co = nn & 511;
    int head = co >> 6, d = co & 63;
    u16* dst = (which == 0) ? Q : (which == 1) ? K : V;
    float sc = (which == 0) ? 0.125f : 1.f;
#pragma unroll
    for (int mr = 0; mr < 4; ++mr) {
      int mb = m0 + wr * 64 + mr * 16 + l4 * 4;
#pragma unroll
      for (int r = 0; r < 4; ++r) {
        int m = mb + r;
        int bb = m >> 10, ii = m & 1023;
        dst[((((size_t)bb * 8 + head) << 10) + ii) * 64 + d] =
            f2bf(acc[mr][nr][r] * sc);
      }
    }
  }
}

// ---------- Kernel 2: S = Q @ K^T per (b,h), bf16 MFMA, out fp8 ----------
__global__ __launch_bounds__(256) void k_qk(const u16* __restrict__ Q,
                                            const u16* __restrict__ Kp,
                                            unsigned char* __restrict__ S8) {
  const int bh = blockIdx.z;
  const u16* Qb = Q + (size_t)bh * 65536;
  const u16* Kb = Kp + (size_t)bh * 65536;
  __shared__ __align__(16) u16 sQ[128 * 64];
  __shared__ __align__(16) u16 sK[128 * 64];
  const int tid = threadIdx.x;
  const int m0 = blockIdx.x * 128, n0 = blockIdx.y * 128;
  {
    int row = tid >> 1, half = tid & 1;
    const u16* gq = &Qb[(size_t)(m0 + row) * 64 + half * 32];
    const u16* gk = &Kb[(size_t)(n0 + row) * 64 + half * 32];
    int xr = row & 7;
#pragma unroll
    for (int q = 0; q < 4; ++q) {
      int gp = (half * 4 + q) ^ xr;
      *(uint4*)&sQ[row * 64 + gp * 8] = *(const uint4*)&gq[q * 8];
      *(uint4*)&sK[row * 64 + gp * 8] = *(const uint4*)&gk[q * 8];
    }
  }
  __syncthreads();
  const int lane = tid & 63, wid = tid >> 6;
  const int wr = wid >> 1, wc = wid & 1;
  const int l15 = lane & 15, l4 = lane >> 4;
  f32x4 acc[4][4] = {};
  bf16x8 af[4][2], bf[4][2];
#pragma unroll
  for (int mr = 0; mr < 4; ++mr) {
    int row = wr * 64 + mr * 16 + l15;
#pragma unroll
    for (int ks = 0; ks < 2; ++ks)
      af[mr][ks] = *(bf16x8*)&sQ[row * 64 + ((ks * 4 + l4) ^ (row & 7)) * 8];
  }
#pragma unroll
  for (int nr = 0; nr < 4; ++nr) {
    int row = wc * 64 + nr * 16 + l15;
#pragma unroll
    for (int ks = 0; ks < 2; ++ks)
      bf[nr][ks] = *(bf16x8*)&sK[row * 64 + ((ks * 4 + l4) ^ (row & 7)) * 8];
  }
#pragma unroll
  for (int mr = 0; mr < 4; ++mr)
#pragma unroll
    for (int nr = 0; nr < 4; ++nr)
#pragma unroll
      for (int ks = 0; ks < 2; ++ks)
        acc[mr][nr] = __builtin_amdgcn_mfma_f32_16x16x32_bf16(af[mr][ks], bf[nr][ks],
                                                              acc[mr][nr], 0, 0, 0);
  __syncthreads();
  unsigned char* t8 = (unsigned char*)sQ;  // reuse 16KB as fp8 [128][128]
#pragma unroll
  for (int mr = 0; mr < 4; ++mr) {
    int mloc = wr * 64 + mr * 16 + l4 * 4;
#pragma unroll
    for (int nr = 0; nr < 4; ++nr) {
      int nloc = wc * 64 + nr * 16 + l15;
#pragma unroll
      for (int r = 0; r < 4; ++r)
        t8[(mloc + r) * 128 + nloc] = f2fp8(acc[mr][nr][r]);
    }
  }
  __syncthreads();
  {
    int row = tid >> 1, c0 = (tid & 1) * 64;
    unsigned char* dst = &S8[((size_t)bh << 20) + (size_t)(m0 + row) * 1024 + n0 + c0];
#pragma unroll
    for (int q = 0; q < 4; ++q)
      *(uint4*)&dst[q * 16] = *(uint4*)&t8[row * 128 + c0 + q * 16];
  }
}

// ---------- Kernel 3: conv3x3(heads)+BN+sigmoid+exp, all-fp8 MFMA GEMM ----------
// Block per (b, row-pair, j-half). TRANSPOSED output C[j][m]. LDS 22.8KB.
// Staging: v_perm 4x4 byte transpose, block-uniform edge branch, natural
// column order (bank conflicts proven timing-neutral).
__global__ __launch_bounds__(256) void k_conv(
    const unsigned char* __restrict__ S8, unsigned char* __restrict__ P8,
    float* __restrict__ Dbuf, const float* __restrict__ cw,
    const float* __restrict__ cb, const float* __restrict__ bg,
    const float* __restrict__ bb, const float* __restrict__ bm,
    const float* __restrict__ bv) {
  const int blk = blockIdx.x;
  const int b = blk >> 10;
  const int rem = blk & 1023;
  const int ip = rem >> 1, jh = rem & 1;
  const int i0 = ip * 2, j0 = jh * 512;
  __shared__ __align__(16) unsigned char sC[514 * 40];  // [ci][k], 40B pitch
  __shared__ __align__(8) unsigned char sA[3][16][40];  // weights per tap, fp8
  __shared__ float sRedD[4][16];
  const int tid = threadIdx.x;
  const int lane = tid & 63, wid = tid >> 6;
  const int l15 = lane & 15, l4 = lane >> 4;

  // Build weight matrix fp8 (folded with BN scale). 1536 entries.
  for (int u = tid; u < 1536; u += 256) {
    int tap = u >> 9, rem2 = u & 511;
    int m = rem2 >> 5, kk = rem2 & 31;
    int p = m >> 3, oh = m & 7;
    int ih = kk >> 2, rr = kk & 3;
    int dr = rr - p;
    float v = 0.f;
    if (dr >= 0 && dr < 3) {
      float ah = bg[oh] * rsqrtf(bv[oh] + 1e-5f);
      v = cw[((oh * 8 + ih) * 3 + dr) * 3 + tap] * ah;
    }
    sA[tap][m][kk] = f2fp8(v);
  }
  // Boundary columns ci=0 (global j0-1) and ci=513 (global j0+512).
  if (tid < 16) {
    int side = tid & 1, ih = tid >> 1;
    int g = side ? (j0 + 512) : (j0 - 1);
    u32 v = 0;
    if (g >= 0 && g < 1024) {
      const unsigned char* Sb = S8 + (((size_t)(b * 8 + ih)) << 20);
#pragma unroll
      for (int rr = 0; rr < 4; ++rr) {
        int r = i0 - 1 + rr;
        u32 byte = (r >= 0 && r < 1024) ? (u32)Sb[(size_t)r * 1024 + g] : 0u;
        v |= byte << (8 * rr);
      }
    }
    *(u32*)&sC[(side ? 513 : 0) * 40 + ih * 4] = v;
  }
  // Main staging: 512 cols. u32 loads (base + offset imm) + v_perm transpose.
  {
    const int ihs = tid >> 5;
    const int lc = tid & 31;
    const unsigned char* p1 =
        S8 + (((size_t)(b * 8 + ihs)) << 20) + (size_t)i0 * 1024 + j0 + lc * 4;
    const bool intr = (i0 != 0) && (i0 != 1022);
#pragma unroll
    for (int it = 0; it < 4; ++it) {
      const unsigned char* pp = p1 + it * 128;
      u32 w0, w3;
      u32 w1 = *(const u32*)pp;
      u32 w2 = *(const u32*)(pp + 1024);
      if (intr) {
        w0 = *(const u32*)(pp - 1024);
        w3 = *(const u32*)(pp + 2048);
      } else {
        w0 = (i0 != 0) ? *(const u32*)(pp - 1024) : 0u;
        w3 = (i0 != 1022) ? *(const u32*)(pp + 2048) : 0u;
      }
      u32 p01l = __builtin_amdgcn_perm(w1, w0, 0x05010400u);
      u32 p23l = __builtin_amdgcn_perm(w3, w2, 0x05010400u);
      u32 p01h = __builtin_amdgcn_perm(w1, w0, 0x07030602u);
      u32 p23h = __builtin_amdgcn_perm(w3, w2, 0x07030602u);
      unsigned char* dst = &sC[(lc * 4 + it * 128 + 1) * 40 + ihs * 4];
      *(u32*)(dst + 0)   = __builtin_amdgcn_perm(p23l, p01l, 0x05040100u);
      *(u32*)(dst + 40)  = __builtin_amdgcn_perm(p23l, p01l, 0x07060302u);
      *(u32*)(dst + 80)  = __builtin_amdgcn_perm(p23h, p01h, 0x05040100u);
      *(u32*)(dst + 120) = __builtin_amdgcn_perm(p23h, p01h, 0x07060302u);
    }
  }
  __syncthreads();

  long wfr[3];
#pragma unroll
  for (int tap = 0; tap < 3; ++tap)
    wfr[tap] = *(long*)&sA[tap][l15][l4 * 8];
  const int oh = l15 & 7, p = l15 >> 3;
  const float ah = bg[oh] * rsqrtf(bv[oh] + 1e-5f);
  const float biasm = cb[oh] * ah + bb[oh] - bm[oh] * ah;
  const int jw = wid * 128;
  unsigned char* Pst = &P8[((size_t)(b * 8 + oh) << 20) + ((size_t)(i0 + p) << 10) +
                           j0 + jw + l4 * 4];
  const unsigned char* sCb = &sC[(size_t)(jw + l15) * 40 + l4 * 8];
  float dsum = 0.f;

  for (int t = 0; t < 8; ++t) {
    f32x4 acc = {0.f, 0.f, 0.f, 0.f};
#pragma unroll
    for (int tap = 0; tap < 3; ++tap) {
      long sfr = *(long*)(sCb + t * 640 + tap * 40);
      acc = __builtin_amdgcn_mfma_f32_16x16x32_fp8_fp8(sfr, wfr[tap], acc, 0, 0, 0);
    }
    float e[4];
#pragma unroll
    for (int r = 0; r < 4; ++r) {
      float tt = acc[r] + biasm;
      float sg = 1.f / (1.f + __expf(-tt));
      e[r] = __expf(sg);  // softmax numerator; sg in (0,1) so no max needed
    }
    *(u32*)(Pst + t * 16) = pk4_fp8(e[0], e[1], e[2], e[3]);
    dsum += (e[0] + e[1]) + (e[2] + e[3]);
  }
  // Reduce across the 4 lanes sharing m=l15 (l4 = lane bits 4-5).
  dsum += __shfl_xor(dsum, 16);
  dsum += __shfl_xor(dsum, 32);
  if (l4 == 0) sRedD[wid][l15] = dsum;
  __syncthreads();
  if (tid < 16) {
    int pp = tid >> 3, ohh = tid & 7;
    Dbuf[(size_t)jh * 65536 + ((size_t)(b * 8 + ohh) << 10) + i0 + pp] =
        sRedD[0][tid] + sRedD[1][tid] + sRedD[2][tid] + sRedD[3][tid];
  }
}

// ---------- Kernel 4: Z = (P @ V) / (D0+D1) per (b,h), fp8 MFMA ----------
__global__ __launch_bounds__(256) void k_av(const unsigned char* __restrict__ P8,
                                            const u16* __restrict__ V,
                                            const float* __restrict__ Dbuf,
                                            u16* __restrict__ Z) {
  const int bh = blockIdx.y, m0 = blockIdx.x * 128;
  const int b = bh >> 3, h = bh & 7;
  __shared__ __align__(16) unsigned char sA8[128 * 64];
  __shared__ __align__(16) unsigned char sVt[64 * 64];
  const int tid = threadIdx.x, lane = tid & 63, wid = tid >> 6;
  const int wr = wid >> 1, wc = wid & 1, l15 = lane & 15, l4 = lane >> 4;
  f32x4 acc[4][2] = {};
  for (int k0 = 0; k0 < 1024; k0 += 64) {
    __syncthreads();
    {  // stage A (P fp8), swizzled
      int row = tid >> 1, c0 = (tid & 1) * 32;
      const unsigned char* src =
          &P8[((size_t)bh << 20) + (size_t)(m0 + row) * 1024 + k0 + c0];
      uint4 a0 = *(const uint4*)src, a1 = *(const uint4*)(src + 16);
      u64 ul[4];
      ul[0] = (u64)a0.x | ((u64)a0.y << 32);
      ul[1] = (u64)a0.z | ((u64)a0.w << 32);
      ul[2] = (u64)a1.x | ((u64)a1.y << 32);
      ul[3] = (u64)a1.z | ((u64)a1.w << 32);
      int xr = row & 7, gb = c0 >> 3;
#pragma unroll
      for (int t = 0; t < 4; ++t)
        *(u64*)&sA8[row * 64 + ((gb + t) ^ xr) * 8] = ul[t];
    }
    {  // stage V^T as fp8, swizzled
      int j = tid >> 2, d0 = (tid & 3) * 16;
      const u16* src = &V[((size_t)bh << 16) + (size_t)(k0 + j) * 64 + d0];
      uint4 v0 = *(const uint4*)src, v1 = *(const uint4*)(src + 16);
      u32 wv[8] = {v0.x, v0.y, v0.z, v0.w, v1.x, v1.y, v1.z, v1.w};
#pragma unroll
      for (int t = 0; t < 8; ++t) {
        u32 p = (u32)__builtin_amdgcn_cvt_pk_fp8_f32(bflo(wv[t]), bfhi(wv[t]), 0, false);
        int da = d0 + t * 2, db = da + 1;
        sVt[da * 64 + (((j >> 3) ^ (da & 7)) << 3) + (j & 7)] = (unsigned char)(p & 0xff);
        sVt[db * 64 + (((j >> 3) ^ (db & 7)) << 3) + (j & 7)] = (unsigned char)((p >> 8) & 0xff);
      }
    }
    __syncthreads();
    long bfr[2][2];
#pragma unroll
    for (int nr = 0; nr < 2; ++nr) {
      int row = wc * 32 + nr * 16 + l15;
#pragma unroll
      for (int ks = 0; ks < 2; ++ks)
        bfr[nr][ks] = *(long*)&sVt[row * 64 + (((ks * 4 + l4) ^ (row & 7)) << 3)];
    }
#pragma unroll
    for (int mr = 0; mr < 4; ++mr) {
      int row = wr * 64 + mr * 16 + l15;
      long afr[2];
#pragma unroll
      for (int ks = 0; ks < 2; ++ks)
        afr[ks] = *(long*)&sA8[row * 64 + (((ks * 4 + l4) ^ (row & 7)) << 3)];
#pragma unroll
      for (int nr = 0; nr < 2; ++nr)
#pragma unroll
        for (int ks = 0; ks < 2; ++ks)
          acc[mr][nr] = __builtin_amdgcn_mfma_f32_16x16x32_fp8_fp8(afr[ks], bfr[nr][ks],
                                                                   acc[mr][nr], 0, 0, 0);
    }
  }
#pragma unroll
  for (int mr = 0; mr < 4; ++mr) {
    int mbase = m0 + wr * 64 + mr * 16 + l4 * 4;
    float dv[4];
#pragma unroll
    for (int r = 0; r < 4; ++r) {
      size_t di = ((size_t)bh << 10) + mbase + r;
      dv[r] = 1.f / (Dbuf[di] + Dbuf[di + 65536]);
    }
#pragma unroll
    for (int nr = 0; nr < 2; ++nr) {
      int d = wc * 32 + nr * 16 + l15;
#pragma unroll
      for (int r = 0; r < 4; ++r)
        Z[((size_t)(b * 1024 + mbase + r)) * 512 + h * 64 + d] =
            f2bf(acc[mr][nr][r] * dv[r]);
    }
  }
}

// ---------- Kernel 5: out = Z @ W^T + b + x, bf16 MFMA. M=8192,N=512,K=512 ----------
__global__ __launch_bounds__(256) void k_proj(const u16* __restrict__ Z,
                                              const float* __restrict__ w,
                                              const float* __restrict__ bias,
                                              const float* __restrict__ xin,
                                              float* __restrict__ out) {
  __shared__ __align__(16) u16 sA[128 * 64];
  __shared__ __align__(16) u16 sB[128 * 64];
  const int tid = threadIdx.x;
  const int m0 = blockIdx.x * 128, n0 = blockIdx.y * 128;
  const int lane = tid & 63, wid = tid >> 6;
  const int wr = wid >> 1, wc = wid & 1;
  const int l15 = lane & 15, l4 = lane >> 4;
  const int row = tid >> 1, half = tid & 1, xr = row & 7;
  f32x4 acc[4][4] = {};
  for (int k0 = 0; k0 < 512; k0 += 64) {
    __syncthreads();
    {
      const u16* gz = &Z[(size_t)(m0 + row) * 512 + k0 + half * 32];
      const float* gb = &w[(size_t)(n0 + row) * 512 + k0 + half * 32];
#pragma unroll
      for (int q = 0; q < 4; ++q) {
        int gp = (half * 4 + q) ^ xr;
        *(uint4*)&sA[row * 64 + gp * 8] = *(const uint4*)&gz[q * 8];
        float4 b0 = *(const float4*)&gb[q * 8];
        float4 b1 = *(const float4*)&gb[q * 8 + 4];
        uint4 pb;
        pb.x = cvtpk_bf16(b0.x, b0.y); pb.y = cvtpk_bf16(b0.z, b0.w);
        pb.z = cvtpk_bf16(b1.x, b1.y); pb.w = cvtpk_bf16(b1.z, b1.w);
        *(uint4*)&sB[row * 64 + gp * 8] = pb;
      }
    }
    __syncthreads();
#pragma unroll
    for (int ks = 0; ks < 2; ++ks) {
      bf16x8 af[4], bfr[4];
#pragma unroll
      for (int mr = 0; mr < 4; ++mr) {
        int rr = wr * 64 + mr * 16 + l15;
        af[mr] = *(bf16x8*)&sA[rr * 64 + ((ks * 4 + l4) ^ (rr & 7)) * 8];
      }
#pragma unroll
      for (int nr = 0; nr < 4; ++nr) {
        int rr = wc * 64 + nr * 16 + l15;
        bfr[nr] = *(bf16x8*)&sB[rr * 64 + ((ks * 4 + l4) ^ (rr & 7)) * 8];
      }
#pragma unroll
      for (int mr = 0; mr < 4; ++mr)
#pragma unroll
        for (int nr = 0; nr < 4; ++nr)
          acc[mr][nr] = __builtin_amdgcn_mfma_f32_16x16x32_bf16(af[mr], bfr[nr],
                                                                acc[mr][nr], 0, 0, 0);
    }
  }
#pragma unroll
  for (int nr = 0; nr < 4; ++nr) {
    int nn = n0 + wc * 64 + nr * 16 + l15;
    float bv2 = bias[nn];
#pragma unroll
    for (int mr = 0; mr < 4; ++mr) {
      int mb = m0 + wr * 64 + mr * 16 + l4 * 4;
#pragma unroll
      for (int r = 0; r < 4; ++r) {
        size_t o = (size_t)(mb + r) * 512 + nn;
        out[o] = acc[mr][nr][r] + bv2 + xin[o];
      }
    }
  }
}

extern "C" void kernel_launch(void* const* d_in, const int* in_sizes, int n_in,
                              void* d_out, int out_size, void* d_ws, size_t ws_size,
                              hipStream_t stream) {
  const size_t need = 160ull << 20;
  if (ws_size < need) return;  // clean diagnostic failure instead of GPU fault

  const float* x      = (const float*)d_in[0];
  const float* qkv_w  = (const float*)d_in[1];
  const float* proj_w = (const float*)d_in[2];
  const float* proj_b = (const float*)d_in[3];
  const float* conv_w = (const float*)d_in[4];
  const float* conv_b = (const float*)d_in[5];
  const float* bn_g   = (const float*)d_in[6];
  const float* bn_b   = (const float*)d_in[7];
  const float* bn_m   = (const float*)d_in[8];
  const float* bn_v   = (const float*)d_in[9];
  float* out = (float*)d_out;

  char* W = (char*)d_ws;
  u16* Wq = (u16*)W;                       // Q bf16 8MB; dead after k_qk
  float* Dbuf = (float*)W;                 // D f32 2x256KB, overlays Q region
  u16* Wk = (u16*)(W + (8ull << 20));
  u16* Wv = (u16*)(W + (16ull << 20));
  u16* Wz = (u16*)(W + (24ull << 20));
  unsigned char* S8 = (unsigned char*)(W + (32ull << 20));  // 64MB
  unsigned char* P8 = (unsigned char*)(W + (96ull << 20));  // 64MB

  k_qkv<<<dim3(64, 12), 256, 0, stream>>>(x, qkv_w, Wq, Wk, Wv);
  k_qk<<<dim3(8, 8, 64), 256, 0, stream>>>(Wq, Wk, S8);
  k_conv<<<dim3(8192), 256, 0, stream>>>(S8, P8, Dbuf, conv_w, conv_b, bn_g, bn_b,
                                         bn_m, bn_v);
  k_av<<<dim3(8, 64), 256, 0, stream>>>(P8, Wv, Dbuf, Wz);
  k_proj<<<dim3(64, 4), 256, 0, stream>>>(Wz, proj_w, proj_b, x, out);
}

// Round 18
// 184.950 us; speedup vs baseline: 1.2956x; 1.1657x over previous
//
#include <hip/hip_runtime.h>

// GuidedAttention on MI355X, round 18: round-17 base (215.6us) + one-time
// f32->bf16 conversion of x / qkv_w / proj_w (3 tiny kernels) so k_qkv and
// k_proj read bf16 with pure-copy staging (halves their operand re-read
// bytes: 384MB -> 192MB for k_qkv; removes ~256 redundant cvt/thread).
// Conversions use the same v_cvt_pk_bf16_f32 -> GEMM inputs bit-identical.
// ws layout (160 MB): [Q bf16 8MB | Dbuf 512KB | PWb bf16 512KB @+1MB]
//                     [K bf16 8MB][V bf16 8MB][Z bf16 8MB]
//                     [S fp8 64MB | Xb bf16 8MB + QWb 1.5MB pre-k_qk]
//                     [P fp8 64MB]

#define DINL __device__ __forceinline__
typedef unsigned short u16;
typedef unsigned int u32;
typedef unsigned long long u64;
typedef short bf16x8 __attribute__((ext_vector_type(8)));
typedef float f32x4 __attribute__((ext_vector_type(4)));

DINL u16 f2bf(float f) {
  u32 u = __float_as_uint(f);
  u += 0x7fffu + ((u >> 16) & 1u);
  return (u16)(u >> 16);
}
DINL float bflo(u32 u) { return __uint_as_float(u << 16); }
DINL float bfhi(u32 u) { return __uint_as_float(u & 0xffff0000u); }
DINL u32 cvtpk_bf16(float lo, float hi) {
  u32 r;
  asm("v_cvt_pk_bf16_f32 %0, %1, %2" : "=v"(r) : "v"(lo), "v"(hi));
  return r;
}
DINL u32 pk4_fp8(float a, float b, float c, float d) {
  u32 r = 0;
  r = (u32)__builtin_amdgcn_cvt_pk_fp8_f32(a, b, (int)r, false);
  r = (u32)__builtin_amdgcn_cvt_pk_fp8_f32(c, d, (int)r, true);
  return r;
}
DINL unsigned char f2fp8(float v) {
  return (unsigned char)((u32)__builtin_amdgcn_cvt_pk_fp8_f32(v, v, 0, false) & 0xffu);
}

// ---------- Kernel 0: f32 -> bf16 (grid-stride, 8 elems/thread/iter) ----------
__global__ __launch_bounds__(256) void k_cvt(const float* __restrict__ in,
                                             u16* __restrict__ out, int n8) {
  int gid = blockIdx.x * 256 + threadIdx.x;
  int stride = gridDim.x * 256;
  for (int i = gid; i < n8; i += stride) {
    float4 a = *(const float4*)&in[(size_t)i * 8];
    float4 b = *(const float4*)&in[(size_t)i * 8 + 4];
    uint4 p;
    p.x = cvtpk_bf16(a.x, a.y); p.y = cvtpk_bf16(a.z, a.w);
    p.z = cvtpk_bf16(b.x, b.y); p.w = cvtpk_bf16(b.z, b.w);
    *(uint4*)&out[(size_t)i * 8] = p;
  }
}

// ---------- Kernel 1: QKV proj, bf16 MFMA. M=8192, N=1536, K=512 ----------
// Inputs pre-converted to bf16 -> staging is pure uint4 copy.
__global__ __launch_bounds__(256) void k_qkv(const u16* __restrict__ xb,
                                             const u16* __restrict__ wb,
                                             u16* __restrict__ Q,
                                             u16* __restrict__ K,
                                             u16* __restrict__ V) {
  __shared__ __align__(16) u16 sA[128 * 64];
  __shared__ __align__(16) u16 sB[128 * 64];
  const int tid = threadIdx.x;
  const int m0 = blockIdx.x * 128, n0 = blockIdx.y * 128;
  const int lane = tid & 63, wid = tid >> 6;
  const int wr = wid >> 1, wc = wid & 1;
  const int l15 = lane & 15, l4 = lane >> 4;
  const int row = tid >> 1, half = tid & 1, xr = row & 7;
  f32x4 acc[4][4] = {};
  for (int k0 = 0; k0 < 512; k0 += 64) {
    __syncthreads();
    {
      const u16* ga = &xb[(size_t)(m0 + row) * 512 + k0 + half * 32];
      const u16* gb = &wb[(size_t)(n0 + row) * 512 + k0 + half * 32];
#pragma unroll
      for (int q = 0; q < 4; ++q) {
        int gp = (half * 4 + q) ^ xr;
        *(uint4*)&sA[row * 64 + gp * 8] = *(const uint4*)&ga[q * 8];
        *(uint4*)&sB[row * 64 + gp * 8] = *(const uint4*)&gb[q * 8];
      }
    }
    __syncthreads();
#pragma unroll
    for (int ks = 0; ks < 2; ++ks) {
      bf16x8 af[4], bfr[4];
#pragma unroll
      for (int mr = 0; mr < 4; ++mr) {
        int rr = wr * 64 + mr * 16 + l15;
        af[mr] = *(bf16x8*)&sA[rr * 64 + ((ks * 4 + l4) ^ (rr & 7)) * 8];
      }
#pragma unroll
      for (int nr = 0; nr < 4; ++nr) {
        int rr = wc * 64 + nr * 16 + l15;
        bfr[nr] = *(bf16x8*)&sB[rr * 64 + ((ks * 4 + l4) ^ (rr & 7)) * 8];
      }
#pragma unroll
      for (int mr = 0; mr < 4; ++mr)
#pragma unroll
        for (int nr = 0; nr < 4; ++nr)
          acc[mr][nr] = __builtin_amdgcn_mfma_f32_16x16x32_bf16(af[mr], bfr[nr],
                                                                acc[mr][nr], 0, 0, 0);
    }
  }
#pragma unroll
  for (int nr = 0; nr < 4; ++nr) {
    int nn = n0 + wc * 64 + nr * 16 + l15;
    int which = nn >> 9, co = nn & 511;
    int head = co >> 6, d = co & 63;
    u16* dst = (which == 0) ? Q : (which == 1) ? K : V;
    float sc = (which == 0) ? 0.125f : 1.f;
#pragma unroll
    for (int mr = 0; mr < 4; ++mr) {
      int mb = m0 + wr * 64 + mr * 16 + l4 * 4;
#pragma unroll
      for (int r = 0; r < 4; ++r) {
        int m = mb + r;
        int bb = m >> 10, ii = m & 1023;
        dst[((((size_t)bb * 8 + head) << 10) + ii) * 64 + d] =
            f2bf(acc[mr][nr][r] * sc);
      }
    }
  }
}

// ---------- Kernel 2: S = Q @ K^T per (b,h), bf16 MFMA, out fp8 ----------
__global__ __launch_bounds__(256) void k_qk(const u16* __restrict__ Q,
                                            const u16* __restrict__ Kp,
                                            unsigned char* __restrict__ S8) {
  const int bh = blockIdx.z;
  const u16* Qb = Q + (size_t)bh * 65536;
  const u16* Kb = Kp + (size_t)bh * 65536;
  __shared__ __align__(16) u16 sQ[128 * 64];
  __shared__ __align__(16) u16 sK[128 * 64];
  const int tid = threadIdx.x;
  const int m0 = blockIdx.x * 128, n0 = blockIdx.y * 128;
  {
    int row = tid >> 1, half = tid & 1;
    const u16* gq = &Qb[(size_t)(m0 + row) * 64 + half * 32];
    const u16* gk = &Kb[(size_t)(n0 + row) * 64 + half * 32];
    int xr = row & 7;
#pragma unroll
    for (int q = 0; q < 4; ++q) {
      int gp = (half * 4 + q) ^ xr;
      *(uint4*)&sQ[row * 64 + gp * 8] = *(const uint4*)&gq[q * 8];
      *(uint4*)&sK[row * 64 + gp * 8] = *(const uint4*)&gk[q * 8];
    }
  }
  __syncthreads();
  const int lane = tid & 63, wid = tid >> 6;
  const int wr = wid >> 1, wc = wid & 1;
  const int l15 = lane & 15, l4 = lane >> 4;
  f32x4 acc[4][4] = {};
  bf16x8 af[4][2], bf[4][2];
#pragma unroll
  for (int mr = 0; mr < 4; ++mr) {
    int row = wr * 64 + mr * 16 + l15;
#pragma unroll
    for (int ks = 0; ks < 2; ++ks)
      af[mr][ks] = *(bf16x8*)&sQ[row * 64 + ((ks * 4 + l4) ^ (row & 7)) * 8];
  }
#pragma unroll
  for (int nr = 0; nr < 4; ++nr) {
    int row = wc * 64 + nr * 16 + l15;
#pragma unroll
    for (int ks = 0; ks < 2; ++ks)
      bf[nr][ks] = *(bf16x8*)&sK[row * 64 + ((ks * 4 + l4) ^ (row & 7)) * 8];
  }
#pragma unroll
  for (int mr = 0; mr < 4; ++mr)
#pragma unroll
    for (int nr = 0; nr < 4; ++nr)
#pragma unroll
      for (int ks = 0; ks < 2; ++ks)
        acc[mr][nr] = __builtin_amdgcn_mfma_f32_16x16x32_bf16(af[mr][ks], bf[nr][ks],
                                                              acc[mr][nr], 0, 0, 0);
  __syncthreads();
  unsigned char* t8 = (unsigned char*)sQ;  // reuse 16KB as fp8 [128][128]
#pragma unroll
  for (int mr = 0; mr < 4; ++mr) {
    int mloc = wr * 64 + mr * 16 + l4 * 4;
#pragma unroll
    for (int nr = 0; nr < 4; ++nr) {
      int nloc = wc * 64 + nr * 16 + l15;
#pragma unroll
      for (int r = 0; r < 4; ++r)
        t8[(mloc + r) * 128 + nloc] = f2fp8(acc[mr][nr][r]);
    }
  }
  __syncthreads();
  {
    int row = tid >> 1, c0 = (tid & 1) * 64;
    unsigned char* dst = &S8[((size_t)bh << 20) + (size_t)(m0 + row) * 1024 + n0 + c0];
#pragma unroll
    for (int q = 0; q < 4; ++q)
      *(uint4*)&dst[q * 16] = *(uint4*)&t8[row * 128 + c0 + q * 16];
  }
}

// ---------- Kernel 3: conv3x3(heads)+BN+sigmoid+exp, all-fp8 MFMA GEMM ----------
// (validated round-17 state)
__global__ __launch_bounds__(256) void k_conv(
    const unsigned char* __restrict__ S8, unsigned char* __restrict__ P8,
    float* __restrict__ Dbuf, const float* __restrict__ cw,
    const float* __restrict__ cb, const float* __restrict__ bg,
    const float* __restrict__ bb, const float* __restrict__ bm,
    const float* __restrict__ bv) {
  const int blk = blockIdx.x;
  const int b = blk >> 10;
  const int rem = blk & 1023;
  const int ip = rem >> 1, jh = rem & 1;
  const int i0 = ip * 2, j0 = jh * 512;
  __shared__ __align__(16) unsigned char sC[514 * 40];  // [ci][k], 40B pitch
  __shared__ __align__(8) unsigned char sA[3][16][40];  // weights per tap, fp8
  __shared__ float sRedD[4][16];
  const int tid = threadIdx.x;
  const int lane = tid & 63, wid = tid >> 6;
  const int l15 = lane & 15, l4 = lane >> 4;

  for (int u = tid; u < 1536; u += 256) {
    int tap = u >> 9, rem2 = u & 511;
    int m = rem2 >> 5, kk = rem2 & 31;
    int p = m >> 3, oh = m & 7;
    int ih = kk >> 2, rr = kk & 3;
    int dr = rr - p;
    float v = 0.f;
    if (dr >= 0 && dr < 3) {
      float ah = bg[oh] * rsqrtf(bv[oh] + 1e-5f);
      v = cw[((oh * 8 + ih) * 3 + dr) * 3 + tap] * ah;
    }
    sA[tap][m][kk] = f2fp8(v);
  }
  if (tid < 16) {
    int side = tid & 1, ih = tid >> 1;
    int g = side ? (j0 + 512) : (j0 - 1);
    u32 v = 0;
    if (g >= 0 && g < 1024) {
      const unsigned char* Sb = S8 + (((size_t)(b * 8 + ih)) << 20);
#pragma unroll
      for (int rr = 0; rr < 4; ++rr) {
        int r = i0 - 1 + rr;
        u32 byte = (r >= 0 && r < 1024) ? (u32)Sb[(size_t)r * 1024 + g] : 0u;
        v |= byte << (8 * rr);
      }
    }
    *(u32*)&sC[(side ? 513 : 0) * 40 + ih * 4] = v;
  }
  {
    const int ihs = tid >> 5;
    const int lc = tid & 31;
    const unsigned char* p1 =
        S8 + (((size_t)(b * 8 + ihs)) << 20) + (size_t)i0 * 1024 + j0 + lc * 4;
    const bool intr = (i0 != 0) && (i0 != 1022);
#pragma unroll
    for (int it = 0; it < 4; ++it) {
      const unsigned char* pp = p1 + it * 128;
      u32 w0, w3;
      u32 w1 = *(const u32*)pp;
      u32 w2 = *(const u32*)(pp + 1024);
      if (intr) {
        w0 = *(const u32*)(pp - 1024);
        w3 = *(const u32*)(pp + 2048);
      } else {
        w0 = (i0 != 0) ? *(const u32*)(pp - 1024) : 0u;
        w3 = (i0 != 1022) ? *(const u32*)(pp + 2048) : 0u;
      }
      u32 p01l = __builtin_amdgcn_perm(w1, w0, 0x05010400u);
      u32 p23l = __builtin_amdgcn_perm(w3, w2, 0x05010400u);
      u32 p01h = __builtin_amdgcn_perm(w1, w0, 0x07030602u);
      u32 p23h = __builtin_amdgcn_perm(w3, w2, 0x07030602u);
      unsigned char* dst = &sC[(lc * 4 + it * 128 + 1) * 40 + ihs * 4];
      *(u32*)(dst + 0)   = __builtin_amdgcn_perm(p23l, p01l, 0x05040100u);
      *(u32*)(dst + 40)  = __builtin_amdgcn_perm(p23l, p01l, 0x07060302u);
      *(u32*)(dst + 80)  = __builtin_amdgcn_perm(p23h, p01h, 0x05040100u);
      *(u32*)(dst + 120) = __builtin_amdgcn_perm(p23h, p01h, 0x07060302u);
    }
  }
  __syncthreads();

  long wfr[3];
#pragma unroll
  for (int tap = 0; tap < 3; ++tap)
    wfr[tap] = *(long*)&sA[tap][l15][l4 * 8];
  const int oh = l15 & 7, p = l15 >> 3;
  const float ah = bg[oh] * rsqrtf(bv[oh] + 1e-5f);
  const float biasm = cb[oh] * ah + bb[oh] - bm[oh] * ah;
  const int jw = wid * 128;
  unsigned char* Pst = &P8[((size_t)(b * 8 + oh) << 20) + ((size_t)(i0 + p) << 10) +
                           j0 + jw + l4 * 4];
  const unsigned char* sCb = &sC[(size_t)(jw + l15) * 40 + l4 * 8];
  float dsum = 0.f;

  for (int t = 0; t < 8; ++t) {
    f32x4 acc = {0.f, 0.f, 0.f, 0.f};
#pragma unroll
    for (int tap = 0; tap < 3; ++tap) {
      long sfr = *(long*)(sCb + t * 640 + tap * 40);
      acc = __builtin_amdgcn_mfma_f32_16x16x32_fp8_fp8(sfr, wfr[tap], acc, 0, 0, 0);
    }
    float e[4];
#pragma unroll
    for (int r = 0; r < 4; ++r) {
      float tt = acc[r] + biasm;
      float sg = 1.f / (1.f + __expf(-tt));
      e[r] = __expf(sg);  // softmax numerator; sg in (0,1) so no max needed
    }
    *(u32*)(Pst + t * 16) = pk4_fp8(e[0], e[1], e[2], e[3]);
    dsum += (e[0] + e[1]) + (e[2] + e[3]);
  }
  dsum += __shfl_xor(dsum, 16);
  dsum += __shfl_xor(dsum, 32);
  if (l4 == 0) sRedD[wid][l15] = dsum;
  __syncthreads();
  if (tid < 16) {
    int pp = tid >> 3, ohh = tid & 7;
    Dbuf[(size_t)jh * 65536 + ((size_t)(b * 8 + ohh) << 10) + i0 + pp] =
        sRedD[0][tid] + sRedD[1][tid] + sRedD[2][tid] + sRedD[3][tid];
  }
}

// ---------- Kernel 4: Z = (P @ V) / (D0+D1) per (b,h), fp8 MFMA ----------
__global__ __launch_bounds__(256) void k_av(const unsigned char* __restrict__ P8,
                                            const u16* __restrict__ V,
                                            const float* __restrict__ Dbuf,
                                            u16* __restrict__ Z) {
  const int bh = blockIdx.y, m0 = blockIdx.x * 128;
  const int b = bh >> 3, h = bh & 7;
  __shared__ __align__(16) unsigned char sA8[128 * 64];
  __shared__ __align__(16) unsigned char sVt[64 * 64];
  const int tid = threadIdx.x, lane = tid & 63, wid = tid >> 6;
  const int wr = wid >> 1, wc = wid & 1, l15 = lane & 15, l4 = lane >> 4;
  f32x4 acc[4][2] = {};
  for (int k0 = 0; k0 < 1024; k0 += 64) {
    __syncthreads();
    {  // stage A (P fp8), swizzled
      int row = tid >> 1, c0 = (tid & 1) * 32;
      const unsigned char* src =
          &P8[((size_t)bh << 20) + (size_t)(m0 + row) * 1024 + k0 + c0];
      uint4 a0 = *(const uint4*)src, a1 = *(const uint4*)(src + 16);
      u64 ul[4];
      ul[0] = (u64)a0.x | ((u64)a0.y << 32);
      ul[1] = (u64)a0.z | ((u64)a0.w << 32);
      ul[2] = (u64)a1.x | ((u64)a1.y << 32);
      ul[3] = (u64)a1.z | ((u64)a1.w << 32);
      int xr = row & 7, gb = c0 >> 3;
#pragma unroll
      for (int t = 0; t < 4; ++t)
        *(u64*)&sA8[row * 64 + ((gb + t) ^ xr) * 8] = ul[t];
    }
    {  // stage V^T as fp8, swizzled
      int j = tid >> 2, d0 = (tid & 3) * 16;
      const u16* src = &V[((size_t)bh << 16) + (size_t)(k0 + j) * 64 + d0];
      uint4 v0 = *(const uint4*)src, v1 = *(const uint4*)(src + 16);
      u32 wv[8] = {v0.x, v0.y, v0.z, v0.w, v1.x, v1.y, v1.z, v1.w};
#pragma unroll
      for (int t = 0; t < 8; ++t) {
        u32 p = (u32)__builtin_amdgcn_cvt_pk_fp8_f32(bflo(wv[t]), bfhi(wv[t]), 0, false);
        int da = d0 + t * 2, db = da + 1;
        sVt[da * 64 + (((j >> 3) ^ (da & 7)) << 3) + (j & 7)] = (unsigned char)(p & 0xff);
        sVt[db * 64 + (((j >> 3) ^ (db & 7)) << 3) + (j & 7)] = (unsigned char)((p >> 8) & 0xff);
      }
    }
    __syncthreads();
    long bfr[2][2];
#pragma unroll
    for (int nr = 0; nr < 2; ++nr) {
      int row = wc * 32 + nr * 16 + l15;
#pragma unroll
      for (int ks = 0; ks < 2; ++ks)
        bfr[nr][ks] = *(long*)&sVt[row * 64 + (((ks * 4 + l4) ^ (row & 7)) << 3)];
    }
#pragma unroll
    for (int mr = 0; mr < 4; ++mr) {
      int row = wr * 64 + mr * 16 + l15;
      long afr[2];
#pragma unroll
      for (int ks = 0; ks < 2; ++ks)
        afr[ks] = *(long*)&sA8[row * 64 + (((ks * 4 + l4) ^ (row & 7)) << 3)];
#pragma unroll
      for (int nr = 0; nr < 2; ++nr)
#pragma unroll
        for (int ks = 0; ks < 2; ++ks)
          acc[mr][nr] = __builtin_amdgcn_mfma_f32_16x16x32_fp8_fp8(afr[ks], bfr[nr][ks],
                                                                   acc[mr][nr], 0, 0, 0);
    }
  }
#pragma unroll
  for (int mr = 0; mr < 4; ++mr) {
    int mbase = m0 + wr * 64 + mr * 16 + l4 * 4;
    float dv[4];
#pragma unroll
    for (int r = 0; r < 4; ++r) {
      size_t di = ((size_t)bh << 10) + mbase + r;
      dv[r] = 1.f / (Dbuf[di] + Dbuf[di + 65536]);
    }
#pragma unroll
    for (int nr = 0; nr < 2; ++nr) {
      int d = wc * 32 + nr * 16 + l15;
#pragma unroll
      for (int r = 0; r < 4; ++r)
        Z[((size_t)(b * 1024 + mbase + r)) * 512 + h * 64 + d] =
            f2bf(acc[mr][nr][r] * dv[r]);
    }
  }
}

// ---------- Kernel 5: out = Z @ W^T + b + x, bf16 MFMA. M=8192,N=512,K=512 ----------
// proj_w pre-converted to bf16 -> staging is pure uint4 copy.
__global__ __launch_bounds__(256) void k_proj(const u16* __restrict__ Z,
                                              const u16* __restrict__ wb,
                                              const float* __restrict__ bias,
                                              const float* __restrict__ xin,
                                              float* __restrict__ out) {
  __shared__ __align__(16) u16 sA[128 * 64];
  __shared__ __align__(16) u16 sB[128 * 64];
  const int tid = threadIdx.x;
  const int m0 = blockIdx.x * 128, n0 = blockIdx.y * 128;
  const int lane = tid & 63, wid = tid >> 6;
  const int wr = wid >> 1, wc = wid & 1;
  const int l15 = lane & 15, l4 = lane >> 4;
  const int row = tid >> 1, half = tid & 1, xr = row & 7;
  f32x4 acc[4][4] = {};
  for (int k0 = 0; k0 < 512; k0 += 64) {
    __syncthreads();
    {
      const u16* gz = &Z[(size_t)(m0 + row) * 512 + k0 + half * 32];
      const u16* gb = &wb[(size_t)(n0 + row) * 512 + k0 + half * 32];
#pragma unroll
      for (int q = 0; q < 4; ++q) {
        int gp = (half * 4 + q) ^ xr;
        *(uint4*)&sA[row * 64 + gp * 8] = *(const uint4*)&gz[q * 8];
        *(uint4*)&sB[row * 64 + gp * 8] = *(const uint4*)&gb[q * 8];
      }
    }
    __syncthreads();
#pragma unroll
    for (int ks = 0; ks < 2; ++ks) {
      bf16x8 af[4], bfr[4];
#pragma unroll
      for (int mr = 0; mr < 4; ++mr) {
        int rr = wr * 64 + mr * 16 + l15;
        af[mr] = *(bf16x8*)&sA[rr * 64 + ((ks * 4 + l4) ^ (rr & 7)) * 8];
      }
#pragma unroll
      for (int nr = 0; nr < 4; ++nr) {
        int rr = wc * 64 + nr * 16 + l15;
        bfr[nr] = *(bf16x8*)&sB[rr * 64 + ((ks * 4 + l4) ^ (rr & 7)) * 8];
      }
#pragma unroll
      for (int mr = 0; mr < 4; ++mr)
#pragma unroll
        for (int nr = 0; nr < 4; ++nr)
          acc[mr][nr] = __builtin_amdgcn_mfma_f32_16x16x32_bf16(af[mr], bfr[nr],
                                                                acc[mr][nr], 0, 0, 0);
    }
  }
#pragma unroll
  for (int nr = 0; nr < 4; ++nr) {
    int nn = n0 + wc * 64 + nr * 16 + l15;
    float bv2 = bias[nn];
#pragma unroll
    for (int mr = 0; mr < 4; ++mr) {
      int mb = m0 + wr * 64 + mr * 16 + l4 * 4;
#pragma unroll
      for (int r = 0; r < 4; ++r) {
        size_t o = (size_t)(mb + r) * 512 + nn;
        out[o] = acc[mr][nr][r] + bv2 + xin[o];
      }
    }
  }
}

extern "C" void kernel_launch(void* const* d_in, const int* in_sizes, int n_in,
                              void* d_out, int out_size, void* d_ws, size_t ws_size,
                              hipStream_t stream) {
  const size_t need = 160ull << 20;
  if (ws_size < need) return;  // clean diagnostic failure instead of GPU fault

  const float* x      = (const float*)d_in[0];
  const float* qkv_w  = (const float*)d_in[1];
  const float* proj_w = (const float*)d_in[2];
  const float* proj_b = (const float*)d_in[3];
  const float* conv_w = (const float*)d_in[4];
  const float* conv_b = (const float*)d_in[5];
  const float* bn_g   = (const float*)d_in[6];
  const float* bn_b   = (const float*)d_in[7];
  const float* bn_m   = (const float*)d_in[8];
  const float* bn_v   = (const float*)d_in[9];
  float* out = (float*)d_out;

  char* W = (char*)d_ws;
  u16* Wq = (u16*)W;                       // Q bf16 8MB; dead after k_qk
  float* Dbuf = (float*)W;                 // D f32 2x256KB, overlays Q region
  u16* PWb = (u16*)(W + (1ull << 20));     // proj_w bf16 512KB (after k_qk)
  u16* Wk = (u16*)(W + (8ull << 20));
  u16* Wv = (u16*)(W + (16ull << 20));
  u16* Wz = (u16*)(W + (24ull << 20));
  unsigned char* S8 = (unsigned char*)(W + (32ull << 20));  // 64MB
  u16* Xb = (u16*)S8;                      // x bf16 8MB (dead once k_qk runs)
  u16* QWb = (u16*)(W + (40ull << 20));    // qkv_w bf16 1.5MB (ditto)
  unsigned char* P8 = (unsigned char*)(W + (96ull << 20));  // 64MB

  k_cvt<<<2048, 256, 0, stream>>>(x, Xb, 524288);
  k_cvt<<<384, 256, 0, stream>>>(qkv_w, QWb, 98304);
  k_qkv<<<dim3(64, 12), 256, 0, stream>>>(Xb, QWb, Wq, Wk, Wv);
  k_qk<<<dim3(8, 8, 64), 256, 0, stream>>>(Wq, Wk, S8);
  k_cvt<<<128, 256, 0, stream>>>(proj_w, PWb, 32768);
  k_conv<<<dim3(8192), 256, 0, stream>>>(S8, P8, Dbuf, conv_w, conv_b, bn_g, bn_b,
                                         bn_m, bn_v);
  k_av<<<dim3(8, 64), 256, 0, stream>>>(P8, Wv, Dbuf, Wz);
  k_proj<<<dim3(64, 4), 256, 0, stream>>>(Wz, PWb, proj_b, x, out);
}

// Round 19
// 162.110 us; speedup vs baseline: 1.4781x; 1.1409x over previous
//
#include <hip/hip_runtime.h>

// GuidedAttention on MI355X, round 19: round-18 base (185us) + prologue
// hoisting: k_prep bakes the conv-weight fp8 matrix [3][16][40] + biasm[8]
// ONCE (was rebuilt per-block by all 8192 k_conv blocks: int-div chains,
// scattered cw loads, per-thread rsqrt) and does the proj_w bf16 cvt.
// x+qkv_w cvt merged into one kernel. 8 -> 7 launches. Math bit-identical.
// ws layout (160 MB): [Q 8MB | Dbuf 512KB | PWb @+1MB | wbake/bbake @+2MB]
//                     [K bf16 8MB][V bf16 8MB][Z bf16 8MB]
//                     [S fp8 64MB | Xb bf16 8MB + QWb 1.5MB pre-k_qk]
//                     [P fp8 64MB]

#define DINL __device__ __forceinline__
typedef unsigned short u16;
typedef unsigned int u32;
typedef unsigned long long u64;
typedef short bf16x8 __attribute__((ext_vector_type(8)));
typedef float f32x4 __attribute__((ext_vector_type(4)));

DINL u16 f2bf(float f) {
  u32 u = __float_as_uint(f);
  u += 0x7fffu + ((u >> 16) & 1u);
  return (u16)(u >> 16);
}
DINL float bflo(u32 u) { return __uint_as_float(u << 16); }
DINL float bfhi(u32 u) { return __uint_as_float(u & 0xffff0000u); }
DINL u32 cvtpk_bf16(float lo, float hi) {
  u32 r;
  asm("v_cvt_pk_bf16_f32 %0, %1, %2" : "=v"(r) : "v"(lo), "v"(hi));
  return r;
}
DINL u32 pk4_fp8(float a, float b, float c, float d) {
  u32 r = 0;
  r = (u32)__builtin_amdgcn_cvt_pk_fp8_f32(a, b, (int)r, false);
  r = (u32)__builtin_amdgcn_cvt_pk_fp8_f32(c, d, (int)r, true);
  return r;
}
DINL unsigned char f2fp8(float v) {
  return (unsigned char)((u32)__builtin_amdgcn_cvt_pk_fp8_f32(v, v, 0, false) & 0xffu);
}

// ---------- Kernel 0a: x + qkv_w f32 -> bf16 (merged, grid-stride) ----------
__global__ __launch_bounds__(256) void k_cvt_xw(const float* __restrict__ x,
                                                const float* __restrict__ qw,
                                                u16* __restrict__ Xb,
                                                u16* __restrict__ QWb) {
  int gid = blockIdx.x * 256 + threadIdx.x;
  int stride = gridDim.x * 256;
  for (int i = gid; i < 622592; i += stride) {
    const float* src;
    u16* dst;
    size_t off;
    if (i < 524288) { src = x; dst = Xb; off = (size_t)i * 8; }
    else { src = qw; dst = QWb; off = (size_t)(i - 524288) * 8; }
    float4 a = *(const float4*)&src[off];
    float4 b = *(const float4*)&src[off + 4];
    uint4 p;
    p.x = cvtpk_bf16(a.x, a.y); p.y = cvtpk_bf16(a.z, a.w);
    p.z = cvtpk_bf16(b.x, b.y); p.w = cvtpk_bf16(b.z, b.w);
    *(uint4*)&dst[off] = p;
  }
}

// ---------- Kernel 0b: bake conv weights fp8 + biasm, and proj_w cvt ----------
// Block 0: wbake[3][16][40] (1536 real entries) + bbake[8].
// Blocks 1..128: proj_w f32->bf16 (32768 groups of 8).
__global__ __launch_bounds__(256) void k_prep(
    const float* __restrict__ cw, const float* __restrict__ cb,
    const float* __restrict__ bg, const float* __restrict__ bb,
    const float* __restrict__ bm, const float* __restrict__ bv,
    const float* __restrict__ proj_w, unsigned char* __restrict__ wbake,
    float* __restrict__ bbake, u16* __restrict__ PWb) {
  const int blk = blockIdx.x, tid = threadIdx.x;
  if (blk == 0) {
    for (int u = tid; u < 1536; u += 256) {
      int tap = u >> 9, rem2 = u & 511;
      int m = rem2 >> 5, kk = rem2 & 31;
      int p = m >> 3, oh = m & 7;
      int ih = kk >> 2, rr = kk & 3;
      int dr = rr - p;
      float v = 0.f;
      if (dr >= 0 && dr < 3) {
        float ah = bg[oh] * rsqrtf(bv[oh] + 1e-5f);
        v = cw[((oh * 8 + ih) * 3 + dr) * 3 + tap] * ah;
      }
      wbake[tap * 640 + m * 40 + kk] = f2fp8(v);
    }
    if (tid < 8) {
      float ah = bg[tid] * rsqrtf(bv[tid] + 1e-5f);
      bbake[tid] = cb[tid] * ah + bb[tid] - bm[tid] * ah;
    }
  } else {
    int i = (blk - 1) * 256 + tid;  // exactly 32768 groups
    float4 a = *(const float4*)&proj_w[(size_t)i * 8];
    float4 b = *(const float4*)&proj_w[(size_t)i * 8 + 4];
    uint4 p;
    p.x = cvtpk_bf16(a.x, a.y); p.y = cvtpk_bf16(a.z, a.w);
    p.z = cvtpk_bf16(b.x, b.y); p.w = cvtpk_bf16(b.z, b.w);
    *(uint4*)&PWb[(size_t)i * 8] = p;
  }
}

// ---------- Kernel 1: QKV proj, bf16 MFMA. M=8192, N=1536, K=512 ----------
__global__ __launch_bounds__(256) void k_qkv(const u16* __restrict__ xb,
                                             const u16* __restrict__ wb,
                                             u16* __restrict__ Q,
                                             u16* __restrict__ K,
                                             u16* __restrict__ V) {
  __shared__ __align__(16) u16 sA[128 * 64];
  __shared__ __align__(16) u16 sB[128 * 64];
  const int tid = threadIdx.x;
  const int m0 = blockIdx.x * 128, n0 = blockIdx.y * 128;
  const int lane = tid & 63, wid = tid >> 6;
  const int wr = wid >> 1, wc = wid & 1;
  const int l15 = lane & 15, l4 = lane >> 4;
  const int row = tid >> 1, half = tid & 1, xr = row & 7;
  f32x4 acc[4][4] = {};
  for (int k0 = 0; k0 < 512; k0 += 64) {
    __syncthreads();
    {
      const u16* ga = &xb[(size_t)(m0 + row) * 512 + k0 + half * 32];
      const u16* gb = &wb[(size_t)(n0 + row) * 512 + k0 + half * 32];
#pragma unroll
      for (int q = 0; q < 4; ++q) {
        int gp = (half * 4 + q) ^ xr;
        *(uint4*)&sA[row * 64 + gp * 8] = *(const uint4*)&ga[q * 8];
        *(uint4*)&sB[row * 64 + gp * 8] = *(const uint4*)&gb[q * 8];
      }
    }
    __syncthreads();
#pragma unroll
    for (int ks = 0; ks < 2; ++ks) {
      bf16x8 af[4], bfr[4];
#pragma unroll
      for (int mr = 0; mr < 4; ++mr) {
        int rr = wr * 64 + mr * 16 + l15;
        af[mr] = *(bf16x8*)&sA[rr * 64 + ((ks * 4 + l4) ^ (rr & 7)) * 8];
      }
#pragma unroll
      for (int nr = 0; nr < 4; ++nr) {
        int rr = wc * 64 + nr * 16 + l15;
        bfr[nr] = *(bf16x8*)&sB[rr * 64 + ((ks * 4 + l4) ^ (rr & 7)) * 8];
      }
#pragma unroll
      for (int mr = 0; mr < 4; ++mr)
#pragma unroll
        for (int nr = 0; nr < 4; ++nr)
          acc[mr][nr] = __builtin_amdgcn_mfma_f32_16x16x32_bf16(af[mr], bfr[nr],
                                                                acc[mr][nr], 0, 0, 0);
    }
  }
#pragma unroll
  for (int nr = 0; nr < 4; ++nr) {
    int nn = n0 + wc * 64 + nr * 16 + l15;
    int which = nn >> 9, co = nn & 511;
    int head = co >> 6, d = co & 63;
    u16* dst = (which == 0) ? Q : (which == 1) ? K : V;
    float sc = (which == 0) ? 0.125f : 1.f;
#pragma unroll
    for (int mr = 0; mr < 4; ++mr) {
      int mb = m0 + wr * 64 + mr * 16 + l4 * 4;
#pragma unroll
      for (int r = 0; r < 4; ++r) {
        int m = mb + r;
        int bb = m >> 10, ii = m & 1023;
        dst[((((size_t)bb * 8 + head) << 10) + ii) * 64 + d] =
            f2bf(acc[mr][nr][r] * sc);
      }
    }
  }
}

// ---------- Kernel 2: S = Q @ K^T per (b,h), bf16 MFMA, out fp8 ----------
__global__ __launch_bounds__(256) void k_qk(const u16* __restrict__ Q,
                                            const u16* __restrict__ Kp,
                                            unsigned char* __restrict__ S8) {
  const int bh = blockIdx.z;
  const u16* Qb = Q + (size_t)bh * 65536;
  const u16* Kb = Kp + (size_t)bh * 65536;
  __shared__ __align__(16) u16 sQ[128 * 64];
  __shared__ __align__(16) u16 sK[128 * 64];
  const int tid = threadIdx.x;
  const int m0 = blockIdx.x * 128, n0 = blockIdx.y * 128;
  {
    int row = tid >> 1, half = tid & 1;
    const u16* gq = &Qb[(size_t)(m0 + row) * 64 + half * 32];
    const u16* gk = &Kb[(size_t)(n0 + row) * 64 + half * 32];
    int xr = row & 7;
#pragma unroll
    for (int q = 0; q < 4; ++q) {
      int gp = (half * 4 + q) ^ xr;
      *(uint4*)&sQ[row * 64 + gp * 8] = *(const uint4*)&gq[q * 8];
      *(uint4*)&sK[row * 64 + gp * 8] = *(const uint4*)&gk[q * 8];
    }
  }
  __syncthreads();
  const int lane = tid & 63, wid = tid >> 6;
  const int wr = wid >> 1, wc = wid & 1;
  const int l15 = lane & 15, l4 = lane >> 4;
  f32x4 acc[4][4] = {};
  bf16x8 af[4][2], bf[4][2];
#pragma unroll
  for (int mr = 0; mr < 4; ++mr) {
    int row = wr * 64 + mr * 16 + l15;
#pragma unroll
    for (int ks = 0; ks < 2; ++ks)
      af[mr][ks] = *(bf16x8*)&sQ[row * 64 + ((ks * 4 + l4) ^ (row & 7)) * 8];
  }
#pragma unroll
  for (int nr = 0; nr < 4; ++nr) {
    int row = wc * 64 + nr * 16 + l15;
#pragma unroll
    for (int ks = 0; ks < 2; ++ks)
      bf[nr][ks] = *(bf16x8*)&sK[row * 64 + ((ks * 4 + l4) ^ (row & 7)) * 8];
  }
#pragma unroll
  for (int mr = 0; mr < 4; ++mr)
#pragma unroll
    for (int nr = 0; nr < 4; ++nr)
#pragma unroll
      for (int ks = 0; ks < 2; ++ks)
        acc[mr][nr] = __builtin_amdgcn_mfma_f32_16x16x32_bf16(af[mr][ks], bf[nr][ks],
                                                              acc[mr][nr], 0, 0, 0);
  __syncthreads();
  unsigned char* t8 = (unsigned char*)sQ;  // reuse 16KB as fp8 [128][128]
#pragma unroll
  for (int mr = 0; mr < 4; ++mr) {
    int mloc = wr * 64 + mr * 16 + l4 * 4;
#pragma unroll
    for (int nr = 0; nr < 4; ++nr) {
      int nloc = wc * 64 + nr * 16 + l15;
#pragma unroll
      for (int r = 0; r < 4; ++r)
        t8[(mloc + r) * 128 + nloc] = f2fp8(acc[mr][nr][r]);
    }
  }
  __syncthreads();
  {
    int row = tid >> 1, c0 = (tid & 1) * 64;
    unsigned char* dst = &S8[((size_t)bh << 20) + (size_t)(m0 + row) * 1024 + n0 + c0];
#pragma unroll
    for (int q = 0; q < 4; ++q)
      *(uint4*)&dst[q * 16] = *(uint4*)&t8[row * 128 + c0 + q * 16];
  }
}

// ---------- Kernel 3: conv3x3(heads)+BN+sigmoid+exp, all-fp8 MFMA GEMM ----------
// Weights/bias pre-baked by k_prep: prologue is a 120x uint4 copy.
__global__ __launch_bounds__(256) void k_conv(
    const unsigned char* __restrict__ S8, unsigned char* __restrict__ P8,
    float* __restrict__ Dbuf, const unsigned char* __restrict__ wbake,
    const float* __restrict__ bbake) {
  const int blk = blockIdx.x;
  const int b = blk >> 10;
  const int rem = blk & 1023;
  const int ip = rem >> 1, jh = rem & 1;
  const int i0 = ip * 2, j0 = jh * 512;
  __shared__ __align__(16) unsigned char sC[514 * 40];  // [ci][k], 40B pitch
  __shared__ __align__(16) unsigned char sA[3][16][40]; // baked weights, fp8
  __shared__ float sRedD[4][16];
  const int tid = threadIdx.x;
  const int lane = tid & 63, wid = tid >> 6;
  const int l15 = lane & 15, l4 = lane >> 4;

  if (tid < 120) ((uint4*)sA)[tid] = ((const uint4*)wbake)[tid];
  if (tid >= 120 && tid < 136) {
    int t = tid - 120;
    int side = t & 1, ih = t >> 1;
    int g = side ? (j0 + 512) : (j0 - 1);
    u32 v = 0;
    if (g >= 0 && g < 1024) {
      const unsigned char* Sb = S8 + (((size_t)(b * 8 + ih)) << 20);
#pragma unroll
      for (int rr = 0; rr < 4; ++rr) {
        int r = i0 - 1 + rr;
        u32 byte = (r >= 0 && r < 1024) ? (u32)Sb[(size_t)r * 1024 + g] : 0u;
        v |= byte << (8 * rr);
      }
    }
    *(u32*)&sC[(side ? 513 : 0) * 40 + ih * 4] = v;
  }
  {
    const int ihs = tid >> 5;
    const int lc = tid & 31;
    const unsigned char* p1 =
        S8 + (((size_t)(b * 8 + ihs)) << 20) + (size_t)i0 * 1024 + j0 + lc * 4;
    const bool intr = (i0 != 0) && (i0 != 1022);
#pragma unroll
    for (int it = 0; it < 4; ++it) {
      const unsigned char* pp = p1 + it * 128;
      u32 w0, w3;
      u32 w1 = *(const u32*)pp;
      u32 w2 = *(const u32*)(pp + 1024);
      if (intr) {
        w0 = *(const u32*)(pp - 1024);
        w3 = *(const u32*)(pp + 2048);
      } else {
        w0 = (i0 != 0) ? *(const u32*)(pp - 1024) : 0u;
        w3 = (i0 != 1022) ? *(const u32*)(pp + 2048) : 0u;
      }
      u32 p01l = __builtin_amdgcn_perm(w1, w0, 0x05010400u);
      u32 p23l = __builtin_amdgcn_perm(w3, w2, 0x05010400u);
      u32 p01h = __builtin_amdgcn_perm(w1, w0, 0x07030602u);
      u32 p23h = __builtin_amdgcn_perm(w3, w2, 0x07030602u);
      unsigned char* dst = &sC[(lc * 4 + it * 128 + 1) * 40 + ihs * 4];
      *(u32*)(dst + 0)   = __builtin_amdgcn_perm(p23l, p01l, 0x05040100u);
      *(u32*)(dst + 40)  = __builtin_amdgcn_perm(p23l, p01l, 0x07060302u);
      *(u32*)(dst + 80)  = __builtin_amdgcn_perm(p23h, p01h, 0x05040100u);
      *(u32*)(dst + 120) = __builtin_amdgcn_perm(p23h, p01h, 0x07060302u);
    }
  }
  __syncthreads();

  long wfr[3];
#pragma unroll
  for (int tap = 0; tap < 3; ++tap)
    wfr[tap] = *(long*)&sA[tap][l15][l4 * 8];
  const int oh = l15 & 7, p = l15 >> 3;
  const float biasm = bbake[oh];
  const int jw = wid * 128;
  unsigned char* Pst = &P8[((size_t)(b * 8 + oh) << 20) + ((size_t)(i0 + p) << 10) +
                           j0 + jw + l4 * 4];
  const unsigned char* sCb = &sC[(size_t)(jw + l15) * 40 + l4 * 8];
  float dsum = 0.f;

  for (int t = 0; t < 8; ++t) {
    f32x4 acc = {0.f, 0.f, 0.f, 0.f};
#pragma unroll
    for (int tap = 0; tap < 3; ++tap) {
      long sfr = *(long*)(sCb + t * 640 + tap * 40);
      acc = __builtin_amdgcn_mfma_f32_16x16x32_fp8_fp8(sfr, wfr[tap], acc, 0, 0, 0);
    }
    float e[4];
#pragma unroll
    for (int r = 0; r < 4; ++r) {
      float tt = acc[r] + biasm;
      float sg = 1.f / (1.f + __expf(-tt));
      e[r] = __expf(sg);  // softmax numerator; sg in (0,1) so no max needed
    }
    *(u32*)(Pst + t * 16) = pk4_fp8(e[0], e[1], e[2], e[3]);
    dsum += (e[0] + e[1]) + (e[2] + e[3]);
  }
  dsum += __shfl_xor(dsum, 16);
  dsum += __shfl_xor(dsum, 32);
  if (l4 == 0) sRedD[wid][l15] = dsum;
  __syncthreads();
  if (tid < 16) {
    int pp = tid >> 3, ohh = tid & 7;
    Dbuf[(size_t)jh * 65536 + ((size_t)(b * 8 + ohh) << 10) + i0 + pp] =
        sRedD[0][tid] + sRedD[1][tid] + sRedD[2][tid] + sRedD[3][tid];
  }
}

// ---------- Kernel 4: Z = (P @ V) / (D0+D1) per (b,h), fp8 MFMA ----------
__global__ __launch_bounds__(256) void k_av(const unsigned char* __restrict__ P8,
                                            const u16* __restrict__ V,
                                            const float* __restrict__ Dbuf,
                                            u16* __restrict__ Z) {
  const int bh = blockIdx.y, m0 = blockIdx.x * 128;
  const int b = bh >> 3, h = bh & 7;
  __shared__ __align__(16) unsigned char sA8[128 * 64];
  __shared__ __align__(16) unsigned char sVt[64 * 64];
  const int tid = threadIdx.x, lane = tid & 63, wid = tid >> 6;
  const int wr = wid >> 1, wc = wid & 1, l15 = lane & 15, l4 = lane >> 4;
  f32x4 acc[4][2] = {};
  for (int k0 = 0; k0 < 1024; k0 += 64) {
    __syncthreads();
    {  // stage A (P fp8), swizzled
      int row = tid >> 1, c0 = (tid & 1) * 32;
      const unsigned char* src =
          &P8[((size_t)bh << 20) + (size_t)(m0 + row) * 1024 + k0 + c0];
      uint4 a0 = *(const uint4*)src, a1 = *(const uint4*)(src + 16);
      u64 ul[4];
      ul[0] = (u64)a0.x | ((u64)a0.y << 32);
      ul[1] = (u64)a0.z | ((u64)a0.w << 32);
      ul[2] = (u64)a1.x | ((u64)a1.y << 32);
      ul[3] = (u64)a1.z | ((u64)a1.w << 32);
      int xr = row & 7, gb = c0 >> 3;
#pragma unroll
      for (int t = 0; t < 4; ++t)
        *(u64*)&sA8[row * 64 + ((gb + t) ^ xr) * 8] = ul[t];
    }
    {  // stage V^T as fp8, swizzled
      int j = tid >> 2, d0 = (tid & 3) * 16;
      const u16* src = &V[((size_t)bh << 16) + (size_t)(k0 + j) * 64 + d0];
      uint4 v0 = *(const uint4*)src, v1 = *(const uint4*)(src + 16);
      u32 wv[8] = {v0.x, v0.y, v0.z, v0.w, v1.x, v1.y, v1.z, v1.w};
#pragma unroll
      for (int t = 0; t < 8; ++t) {
        u32 p = (u32)__builtin_amdgcn_cvt_pk_fp8_f32(bflo(wv[t]), bfhi(wv[t]), 0, false);
        int da = d0 + t * 2, db = da + 1;
        sVt[da * 64 + (((j >> 3) ^ (da & 7)) << 3) + (j & 7)] = (unsigned char)(p & 0xff);
        sVt[db * 64 + (((j >> 3) ^ (db & 7)) << 3) + (j & 7)] = (unsigned char)((p >> 8) & 0xff);
      }
    }
    __syncthreads();
    long bfr[2][2];
#pragma unroll
    for (int nr = 0; nr < 2; ++nr) {
      int row = wc * 32 + nr * 16 + l15;
#pragma unroll
      for (int ks = 0; ks < 2; ++ks)
        bfr[nr][ks] = *(long*)&sVt[row * 64 + (((ks * 4 + l4) ^ (row & 7)) << 3)];
    }
#pragma unroll
    for (int mr = 0; mr < 4; ++mr) {
      int row = wr * 64 + mr * 16 + l15;
      long afr[2];
#pragma unroll
      for (int ks = 0; ks < 2; ++ks)
        afr[ks] = *(long*)&sA8[row * 64 + (((ks * 4 + l4) ^ (row & 7)) << 3)];
#pragma unroll
      for (int nr = 0; nr < 2; ++nr)
#pragma unroll
        for (int ks = 0; ks < 2; ++ks)
          acc[mr][nr] = __builtin_amdgcn_mfma_f32_16x16x32_fp8_fp8(afr[ks], bfr[nr][ks],
                                                                   acc[mr][nr], 0, 0, 0);
    }
  }
#pragma unroll
  for (int mr = 0; mr < 4; ++mr) {
    int mbase = m0 + wr * 64 + mr * 16 + l4 * 4;
    float dv[4];
#pragma unroll
    for (int r = 0; r < 4; ++r) {
      size_t di = ((size_t)bh << 10) + mbase + r;
      dv[r] = 1.f / (Dbuf[di] + Dbuf[di + 65536]);
    }
#pragma unroll
    for (int nr = 0; nr < 2; ++nr) {
      int d = wc * 32 + nr * 16 + l15;
#pragma unroll
      for (int r = 0; r < 4; ++r)
        Z[((size_t)(b * 1024 + mbase + r)) * 512 + h * 64 + d] =
            f2bf(acc[mr][nr][r] * dv[r]);
    }
  }
}

// ---------- Kernel 5: out = Z @ W^T + b + x, bf16 MFMA. M=8192,N=512,K=512 ----------
__global__ __launch_bounds__(256) void k_proj(const u16* __restrict__ Z,
                                              const u16* __restrict__ wb,
                                              const float* __restrict__ bias,
                                              const float* __restrict__ xin,
                                              float* __restrict__ out) {
  __shared__ __align__(16) u16 sA[128 * 64];
  __shared__ __align__(16) u16 sB[128 * 64];
  const int tid = threadIdx.x;
  const int m0 = blockIdx.x * 128, n0 = blockIdx.y * 128;
  const int lane = tid & 63, wid = tid >> 6;
  const int wr = wid >> 1, wc = wid & 1;
  const int l15 = lane & 15, l4 = lane >> 4;
  const int row = tid >> 1, half = tid & 1, xr = row & 7;
  f32x4 acc[4][4] = {};
  for (int k0 = 0; k0 < 512; k0 += 64) {
    __syncthreads();
    {
      const u16* gz = &Z[(size_t)(m0 + row) * 512 + k0 + half * 32];
      const u16* gb = &wb[(size_t)(n0 + row) * 512 + k0 + half * 32];
#pragma unroll
      for (int q = 0; q < 4; ++q) {
        int gp = (half * 4 + q) ^ xr;
        *(uint4*)&sA[row * 64 + gp * 8] = *(const uint4*)&gz[q * 8];
        *(uint4*)&sB[row * 64 + gp * 8] = *(const uint4*)&gb[q * 8];
      }
    }
    __syncthreads();
#pragma unroll
    for (int ks = 0; ks < 2; ++ks) {
      bf16x8 af[4], bfr[4];
#pragma unroll
      for (int mr = 0; mr < 4; ++mr) {
        int rr = wr * 64 + mr * 16 + l15;
        af[mr] = *(bf16x8*)&sA[rr * 64 + ((ks * 4 + l4) ^ (rr & 7)) * 8];
      }
#pragma unroll
      for (int nr = 0; nr < 4; ++nr) {
        int rr = wc * 64 + nr * 16 + l15;
        bfr[nr] = *(bf16x8*)&sB[rr * 64 + ((ks * 4 + l4) ^ (rr & 7)) * 8];
      }
#pragma unroll
      for (int mr = 0; mr < 4; ++mr)
#pragma unroll
        for (int nr = 0; nr < 4; ++nr)
          acc[mr][nr] = __builtin_amdgcn_mfma_f32_16x16x32_bf16(af[mr], bfr[nr],
                                                                acc[mr][nr], 0, 0, 0);
    }
  }
#pragma unroll
  for (int nr = 0; nr < 4; ++nr) {
    int nn = n0 + wc * 64 + nr * 16 + l15;
    float bv2 = bias[nn];
#pragma unroll
    for (int mr = 0; mr < 4; ++mr) {
      int mb = m0 + wr * 64 + mr * 16 + l4 * 4;
#pragma unroll
      for (int r = 0; r < 4; ++r) {
        size_t o = (size_t)(mb + r) * 512 + nn;
        out[o] = acc[mr][nr][r] + bv2 + xin[o];
      }
    }
  }
}

extern "C" void kernel_launch(void* const* d_in, const int* in_sizes, int n_in,
                              void* d_out, int out_size, void* d_ws, size_t ws_size,
                              hipStream_t stream) {
  const size_t need = 160ull << 20;
  if (ws_size < need) return;  // clean diagnostic failure instead of GPU fault

  const float* x      = (const float*)d_in[0];
  const float* qkv_w  = (const float*)d_in[1];
  const float* proj_w = (const float*)d_in[2];
  const float* proj_b = (const float*)d_in[3];
  const float* conv_w = (const float*)d_in[4];
  const float* conv_b = (const float*)d_in[5];
  const float* bn_g   = (const float*)d_in[6];
  const float* bn_b   = (const float*)d_in[7];
  const float* bn_m   = (const float*)d_in[8];
  const float* bn_v   = (const float*)d_in[9];
  float* out = (float*)d_out;

  char* W = (char*)d_ws;
  u16* Wq = (u16*)W;                        // Q bf16 8MB; dead after k_qk
  float* Dbuf = (float*)W;                  // D f32 2x256KB, overlays Q region
  u16* PWb = (u16*)(W + (1ull << 20));      // proj_w bf16 512KB (after k_qk)
  unsigned char* wbake = (unsigned char*)(W + (2ull << 20));  // 1920B
  float* bbake = (float*)(W + (2ull << 20) + 4096);           // 32B
  u16* Wk = (u16*)(W + (8ull << 20));
  u16* Wv = (u16*)(W + (16ull << 20));
  u16* Wz = (u16*)(W + (24ull << 20));
  unsigned char* S8 = (unsigned char*)(W + (32ull << 20));    // 64MB
  u16* Xb = (u16*)S8;                       // x bf16 8MB (dead once k_qk runs)
  u16* QWb = (u16*)(W + (40ull << 20));     // qkv_w bf16 1.5MB (ditto)
  unsigned char* P8 = (unsigned char*)(W + (96ull << 20));    // 64MB

  k_cvt_xw<<<2048, 256, 0, stream>>>(x, qkv_w, Xb, QWb);
  k_qkv<<<dim3(64, 12), 256, 0, stream>>>(Xb, QWb, Wq, Wk, Wv);
  k_qk<<<dim3(8, 8, 64), 256, 0, stream>>>(Wq, Wk, S8);
  k_prep<<<129, 256, 0, stream>>>(conv_w, conv_b, bn_g, bn_b, bn_m, bn_v,
                                  proj_w, wbake, bbake, PWb);
  k_conv<<<dim3(8192), 256, 0, stream>>>(S8, P8, Dbuf, wbake, bbake);
  k_av<<<dim3(8, 64), 256, 0, stream>>>(P8, Wv, Dbuf, Wz);
  k_proj<<<dim3(64, 4), 256, 0, stream>>>(Wz, PWb, proj_b, x, out);
}